// Round 1
// baseline (3827.768 us; speedup 1.0000x reference)
//
#include <hip/hip_runtime.h>

#define TT 8
#define VV 10000
#define EE 160000
#define HH 64
#define NN 16
#define CO 64
#define CONV_OUT 160

__device__ __forceinline__ float wave_sum64(float v) {
#pragma unroll
  for (int m = 32; m > 0; m >>= 1) v += __shfl_xor(v, m, 64);
  return v;
}

// ---- in-degree counts (shared by both layers) ----
__global__ __launch_bounds__(256) void count_kernel(const int* __restrict__ ei, int* __restrict__ cnt) {
  int idx = blockIdx.x * 256 + threadIdx.x;
  if (idx >= TT * EE) return;
  int t = idx / EE, e = idx - t * EE;
  int dst = ei[(t * 2 + 1) * EE + e];
  atomicAdd(&cnt[t * VV + dst], 1);
}

// ---- agg[t,dst,:] += x[t,src,:] ----
template <int CIN>
__global__ __launch_bounds__(256) void agg_kernel(const int* __restrict__ ei, const float* __restrict__ x,
                                                  float* __restrict__ agg) {
  constexpr int CPV = CIN / 4;  // float4 chunks per edge
  int idx = blockIdx.x * 256 + threadIdx.x;
  if (idx >= TT * EE * CPV) return;
  int eg = idx / CPV;
  int cc = (idx - eg * CPV) * 4;
  int t = eg / EE, e = eg - t * EE;
  int src = ei[(t * 2) * EE + e];
  int dst = ei[(t * 2 + 1) * EE + e];
  const float4 xv = *reinterpret_cast<const float4*>(&x[((long)(t * VV + src)) * CIN + cc]);
  float* p = &agg[((long)(t * VV + dst)) * CIN + cc];
  unsafeAtomicAdd(p + 0, xv.x);
  unsafeAtomicAdd(p + 1, xv.y);
  unsafeAtomicAdd(p + 2, xv.z);
  unsafeAtomicAdd(p + 3, xv.w);
}

// ---- fused: outs = x@Wl + (agg@Wr)/cnt + bc ; xsr = x@Wres + bres ----
template <int CIN>
__global__ __launch_bounds__(256) void conv_fused(const float* __restrict__ x, const float* __restrict__ agg,
                                                  const int* __restrict__ cnt, const float* __restrict__ Wl,
                                                  const float* __restrict__ Wr, const float* __restrict__ bc,
                                                  const float* __restrict__ Wres, const float* __restrict__ bres,
                                                  float* __restrict__ outs, float* __restrict__ xsr) {
  constexpr int RB = 16;
  __shared__ float xt[RB][CIN];
  __shared__ float at[RB][CIN];
  __shared__ float ct[RB];
  int tid = threadIdx.x;
  long row0 = (long)blockIdx.x * RB;
  if (tid < RB) ct[tid] = fmaxf((float)cnt[row0 + tid], 1.0f);
  for (int i = tid; i < RB * CIN; i += 256) {
    int r = i / CIN, c = i - r * CIN;
    xt[r][c] = x[(row0 + r) * CIN + c];
    at[r][c] = agg[(row0 + r) * CIN + c];
  }
  __syncthreads();
  if (tid < CONV_OUT) {
    int j = tid;
    float acc[RB], accr[RB];
#pragma unroll
    for (int r = 0; r < RB; r++) { acc[r] = 0.f; accr[r] = 0.f; }
    for (int c = 0; c < CIN; c++) {
      float wl = Wl[c * CONV_OUT + j];
      float wr = Wr[c * CONV_OUT + j];
#pragma unroll
      for (int r = 0; r < RB; r++) {
        acc[r] = fmaf(xt[r][c], wl, acc[r]);
        accr[r] = fmaf(at[r][c], wr, accr[r]);
      }
    }
    float b = bc[j];
#pragma unroll
    for (int r = 0; r < RB; r++) outs[(row0 + r) * CONV_OUT + j] = acc[r] + accr[r] / ct[r] + b;
  } else if (tid >= 192) {
    int h = tid - 192;
    float acc[RB];
#pragma unroll
    for (int r = 0; r < RB; r++) acc[r] = 0.f;
    for (int c = 0; c < CIN; c++) {
      float w = Wres[c * HH + h];
#pragma unroll
      for (int r = 0; r < RB; r++) acc[r] = fmaf(xt[r][c], w, acc[r]);
    }
    float b = bres[h];
#pragma unroll
    for (int r = 0; r < RB; r++) xsr[(row0 + r) * HH + h] = acc[r] + b;
  }
}

// ---- depthwise conv over T (kernel 3, same padding) on xh = outs[...,0:64] ----
__global__ __launch_bounds__(256) void tokenmix_kernel(const float* __restrict__ outs, const float* __restrict__ w,
                                                       const float* __restrict__ b, float* __restrict__ xmix) {
  int idx = blockIdx.x * 256 + threadIdx.x;
  if (idx >= TT * VV * HH) return;
  int h = idx & (HH - 1);
  int tv = idx >> 6;  // t*V + v
  int t = tv / VV;
  float c = outs[(long)tv * CONV_OUT + h] * w[h * 3 + 1];
  if (t > 0) c = fmaf(outs[(long)(tv - VV) * CONV_OUT + h], w[h * 3 + 0], c);
  if (t < TT - 1) c = fmaf(outs[(long)(tv + VV) * CONV_OUT + h], w[h * 3 + 2], c);
  xmix[idx] = c + b[h];
}

// ---- diagonal SSM scan over T: one wave (64 lanes = H) per vertex ----
__global__ __launch_bounds__(256) void ssm_kernel(const float* __restrict__ outs, const float* __restrict__ xin,
                                                  const float* __restrict__ xsr, const float* __restrict__ logA,
                                                  const float* __restrict__ dlt, float* __restrict__ yout,
                                                  int writeAllT) {
  int v = blockIdx.x * 4 + (threadIdx.x >> 6);
  int h = threadIdx.x & 63;
  float A[NN], s[NN];
#pragma unroll
  for (int n = 0; n < NN; n++) {
    A[n] = -__expf(logA[h * NN + n]);
    s[n] = 0.f;
  }
  float dh = dlt[h];
  for (int t = 0; t < TT; t++) {
    long row = (long)t * VV + v;
    float dtr = outs[row * CONV_OUT + HH + h] + dh;
    float dt = dtr > 20.f ? dtr : log1pf(__expf(dtr));
    float xv = xin ? xin[row * HH + h] : outs[row * CONV_OUT + h];
    float r = xsr[row * HH + h];
    float y = 0.f;
#pragma unroll
    for (int n = 0; n < NN; n++) {
      float Bn = outs[row * CONV_OUT + 2 * HH + n];
      float Cn = outs[row * CONV_OUT + 2 * HH + NN + n];
      s[n] = fmaf(__expf(dt * A[n]), s[n], dt * Bn * xv);
      y = fmaf(s[n], Cn, y);
    }
    y = fmaxf(y, 0.f);
    float z = y + r;
    float m = wave_sum64(z) * (1.f / 64.f);
    float d = z - m;
    float var = wave_sum64(d * d) * (1.f / 64.f);
    float o = d * rsqrtf(var + 1e-5f);
    if (writeAllT)
      yout[row * HH + h] = o;
    else if (t == TT - 1)
      yout[(long)v * HH + h] = o;
  }
}

// ---- final [V,64] @ [64,64] + b ----
__global__ __launch_bounds__(256) void final_kernel(const float* __restrict__ y, const float* __restrict__ W,
                                                    const float* __restrict__ b, float* __restrict__ out) {
  int idx = blockIdx.x * 256 + threadIdx.x;
  if (idx >= VV * CO) return;
  int j = idx & 63;
  int v = idx >> 6;
  float acc = b[j];
#pragma unroll
  for (int h = 0; h < HH; h++) acc = fmaf(y[v * HH + h], W[h * CO + j], acc);
  out[idx] = acc;
}

extern "C" void kernel_launch(void* const* d_in, const int* in_sizes, int n_in, void* d_out, int out_size,
                              void* d_ws, size_t ws_size, hipStream_t stream) {
  const float* xs = (const float*)d_in[0];
  const int* ei = (const int*)d_in[1];
  const float* Wl0 = (const float*)d_in[2];
  const float* Wr0 = (const float*)d_in[3];
  const float* bc0 = (const float*)d_in[4];
  const float* Wl1 = (const float*)d_in[5];
  const float* Wr1 = (const float*)d_in[6];
  const float* bc1 = (const float*)d_in[7];
  const float* Wres0 = (const float*)d_in[8];
  const float* bres0 = (const float*)d_in[9];
  const float* Wres1 = (const float*)d_in[10];
  const float* bres1 = (const float*)d_in[11];
  const float* tkw = (const float*)d_in[12];
  const float* tkb = (const float*)d_in[13];
  const float* logA = (const float*)d_in[14];
  const float* dlt = (const float*)d_in[15];
  const float* Wmlp = (const float*)d_in[16];
  const float* bmlp = (const float*)d_in[17];
  float* out = (float*)d_out;

  float* ws = (float*)d_ws;
  const long R = (long)TT * VV;  // 80000 rows
  float* outs = ws;              // R*160
  float* xsr = outs + R * 160;   // R*64
  float* x1 = xsr + R * 64;      // R*64
  float* xmix = x1 + R * 64;     // R*64 (reused as layer-1 final y)
  float* agg = xmix + R * 64;    // R*128
  int* cnt = (int*)(agg + R * 128);  // R ints

  // ---- shared counts ----
  hipMemsetAsync(cnt, 0, R * sizeof(int), stream);
  count_kernel<<<(TT * EE + 255) / 256, 256, 0, stream>>>(ei, cnt);

  // ---- layer 0 ----
  hipMemsetAsync(agg, 0, R * 128 * sizeof(float), stream);
  agg_kernel<128><<<(TT * EE * 32) / 256, 256, 0, stream>>>(ei, xs, agg);
  conv_fused<128><<<R / 16, 256, 0, stream>>>(xs, agg, cnt, Wl0, Wr0, bc0, Wres0, bres0, outs, xsr);
  tokenmix_kernel<<<(TT * VV * HH) / 256, 256, 0, stream>>>(outs, tkw, tkb, xmix);
  ssm_kernel<<<VV / 4, 256, 0, stream>>>(outs, xmix, xsr, logA, dlt, x1, 1);

  // ---- layer 1 ----
  hipMemsetAsync(agg, 0, R * 64 * sizeof(float), stream);
  agg_kernel<64><<<(TT * EE * 16) / 256, 256, 0, stream>>>(ei, x1, agg);
  conv_fused<64><<<R / 16, 256, 0, stream>>>(x1, agg, cnt, Wl1, Wr1, bc1, Wres1, bres1, outs, xsr);
  ssm_kernel<<<VV / 4, 256, 0, stream>>>(outs, nullptr, xsr, logA + HH * NN, dlt + HH, xmix, 0);

  // ---- head ----
  final_kernel<<<(VV * CO) / 256, 256, 0, stream>>>(xmix, Wmlp, bmlp, out);
}

// Round 2
// 934.345 us; speedup vs baseline: 4.0967x; 4.0967x over previous
//
#include <hip/hip_runtime.h>

#define TT 8
#define VV 10000
#define EE 160000
#define HH 64
#define NN 16
#define CO 64
#define CONV_OUT 160
#define RR (TT * VV)

__device__ __forceinline__ float wave_sum64(float v) {
#pragma unroll
  for (int m = 32; m > 0; m >>= 1) v += __shfl_xor(v, m, 64);
  return v;
}

// ---- in-degree counts ----
__global__ __launch_bounds__(256) void count_kernel(const int* __restrict__ ei, int* __restrict__ cnt) {
  int idx = blockIdx.x * 256 + threadIdx.x;
  if (idx >= TT * EE) return;
  int t = idx / EE, e = idx - t * EE;
  int dst = ei[(t * 2 + 1) * EE + e];
  atomicAdd(&cnt[t * VV + dst], 1);
}

// ---- CSR build: block-level exclusive scan ----
__global__ __launch_bounds__(256) void scan_block(const int* __restrict__ cnt, int* __restrict__ off,
                                                  int* __restrict__ bsum) {
  __shared__ int sm[256];
  int i = blockIdx.x * 256 + threadIdx.x;
  int v = (i < RR) ? cnt[i] : 0;
  sm[threadIdx.x] = v;
  __syncthreads();
  for (int d = 1; d < 256; d <<= 1) {
    int t = (threadIdx.x >= d) ? sm[threadIdx.x - d] : 0;
    __syncthreads();
    sm[threadIdx.x] += t;
    __syncthreads();
  }
  if (i < RR) off[i] = sm[threadIdx.x] - v;
  if (threadIdx.x == 255) bsum[blockIdx.x] = sm[255];
}

__global__ __launch_bounds__(512) void scan_tops(int* __restrict__ bsum, int nb) {
  __shared__ int sm[512];
  int v = (threadIdx.x < nb) ? bsum[threadIdx.x] : 0;
  sm[threadIdx.x] = v;
  __syncthreads();
  for (int d = 1; d < 512; d <<= 1) {
    int t = (threadIdx.x >= d) ? sm[threadIdx.x - d] : 0;
    __syncthreads();
    sm[threadIdx.x] += t;
    __syncthreads();
  }
  if (threadIdx.x < nb) bsum[threadIdx.x] = sm[threadIdx.x] - v;
}

__global__ __launch_bounds__(256) void scan_add(int* __restrict__ off, const int* __restrict__ bsum,
                                                int* __restrict__ cursor) {
  int i = blockIdx.x * 256 + threadIdx.x;
  if (i < RR) {
    int o = off[i] + bsum[blockIdx.x];
    off[i] = o;
    cursor[i] = o;
  }
  if (i == 0) off[RR] = TT * EE;
}

__global__ __launch_bounds__(256) void scatter_kernel(const int* __restrict__ ei, int* __restrict__ cursor,
                                                      int* __restrict__ csr) {
  int idx = blockIdx.x * 256 + threadIdx.x;
  if (idx >= TT * EE) return;
  int t = idx / EE, e = idx - t * EE;
  int src = ei[(t * 2) * EE + e];
  int dst = ei[(t * 2 + 1) * EE + e];
  int pos = atomicAdd(&cursor[t * VV + dst], 1);
  csr[pos] = t * VV + src;
}

// ---- gather-based mean-agg numerator: agg[row,:] = sum_{e in CSR[row]} x[src_e,:] ----
template <int CIN>
__global__ __launch_bounds__(256) void gather_kernel(const int* __restrict__ off, const int* __restrict__ csr,
                                                     const float* __restrict__ x, float* __restrict__ agg) {
  constexpr int G = 256 / CIN;  // row-groups per block
  int grp = threadIdx.x / CIN;
  int lane = threadIdx.x - grp * CIN;
  int row = blockIdx.x * G + grp;
  int s = off[row], e = off[row + 1];
  float acc = 0.f;
  for (int i = s; i < e; i++) {
    int gsrc = csr[i];
    acc += x[(long)gsrc * CIN + lane];
  }
  agg[(long)row * CIN + lane] = acc;
}

// ---- fused: outs = x@Wl + (agg@Wr)/cnt + bc ; xsr = x@Wres + bres ----
template <int CIN>
__global__ __launch_bounds__(256) void conv_fused(const float* __restrict__ x, const float* __restrict__ agg,
                                                  const int* __restrict__ cnt, const float* __restrict__ Wl,
                                                  const float* __restrict__ Wr, const float* __restrict__ bc,
                                                  const float* __restrict__ Wres, const float* __restrict__ bres,
                                                  float* __restrict__ outs, float* __restrict__ xsr) {
  constexpr int RB = 16;
  __shared__ float xt[RB][CIN];
  __shared__ float at[RB][CIN];
  __shared__ float ct[RB];
  int tid = threadIdx.x;
  long row0 = (long)blockIdx.x * RB;
  if (tid < RB) ct[tid] = fmaxf((float)cnt[row0 + tid], 1.0f);
  for (int i = tid; i < RB * CIN; i += 256) {
    int r = i / CIN, c = i - r * CIN;
    xt[r][c] = x[(row0 + r) * CIN + c];
    at[r][c] = agg[(row0 + r) * CIN + c];
  }
  __syncthreads();
  if (tid < CONV_OUT) {
    int j = tid;
    float acc[RB], accr[RB];
#pragma unroll
    for (int r = 0; r < RB; r++) { acc[r] = 0.f; accr[r] = 0.f; }
    for (int c = 0; c < CIN; c++) {
      float wl = Wl[c * CONV_OUT + j];
      float wr = Wr[c * CONV_OUT + j];
#pragma unroll
      for (int r = 0; r < RB; r++) {
        acc[r] = fmaf(xt[r][c], wl, acc[r]);
        accr[r] = fmaf(at[r][c], wr, accr[r]);
      }
    }
    float b = bc[j];
#pragma unroll
    for (int r = 0; r < RB; r++) outs[(row0 + r) * CONV_OUT + j] = acc[r] + accr[r] / ct[r] + b;
  } else if (tid >= 192) {
    int h = tid - 192;
    float acc[RB];
#pragma unroll
    for (int r = 0; r < RB; r++) acc[r] = 0.f;
    for (int c = 0; c < CIN; c++) {
      float w = Wres[c * HH + h];
#pragma unroll
      for (int r = 0; r < RB; r++) acc[r] = fmaf(xt[r][c], w, acc[r]);
    }
    float b = bres[h];
#pragma unroll
    for (int r = 0; r < RB; r++) xsr[(row0 + r) * HH + h] = acc[r] + b;
  }
}

// ---- diagonal SSM scan over T (token-mix inlined for layer 0) ----
__global__ __launch_bounds__(256) void ssm_kernel(const float* __restrict__ outs, const float* __restrict__ xsr,
                                                  const float* __restrict__ logA, const float* __restrict__ dlt,
                                                  const float* __restrict__ tkw, const float* __restrict__ tkb,
                                                  float* __restrict__ yout, int mode /*0: tkmix+allT, 1: last only*/) {
  int v = blockIdx.x * 4 + (threadIdx.x >> 6);
  int h = threadIdx.x & 63;
  float A[NN], s[NN];
#pragma unroll
  for (int n = 0; n < NN; n++) {
    A[n] = -__expf(logA[h * NN + n]);
    s[n] = 0.f;
  }
  float dh = dlt[h];
  float w0 = 0.f, w1 = 0.f, w2 = 0.f, tb = 0.f;
  float xhm = 0.f, xh0 = 0.f;
  if (mode == 0) {
    w0 = tkw[h * 3 + 0];
    w1 = tkw[h * 3 + 1];
    w2 = tkw[h * 3 + 2];
    tb = tkb[h];
    xh0 = outs[(long)v * CONV_OUT + h];  // t=0 current
  }
  for (int t = 0; t < TT; t++) {
    long row = (long)t * VV + v;
    float dtr = outs[row * CONV_OUT + HH + h] + dh;
    float dt = dtr > 20.f ? dtr : log1pf(__expf(dtr));
    float xv;
    if (mode == 0) {
      float xh1 = (t < TT - 1) ? outs[(row + VV) * CONV_OUT + h] : 0.f;
      xv = fmaf(xhm, w0, fmaf(xh0, w1, fmaf(xh1, w2, tb)));
      xhm = xh0;
      xh0 = xh1;
    } else {
      xv = outs[row * CONV_OUT + h];
    }
    float r = xsr[row * HH + h];
    float y = 0.f;
#pragma unroll
    for (int n = 0; n < NN; n++) {
      float Bn = outs[row * CONV_OUT + 2 * HH + n];
      float Cn = outs[row * CONV_OUT + 2 * HH + NN + n];
      s[n] = fmaf(__expf(dt * A[n]), s[n], dt * Bn * xv);
      y = fmaf(s[n], Cn, y);
    }
    y = fmaxf(y, 0.f);
    float z = y + r;
    float m = wave_sum64(z) * (1.f / 64.f);
    float d = z - m;
    float var = wave_sum64(d * d) * (1.f / 64.f);
    float o = d * rsqrtf(var + 1e-5f);
    if (mode == 0)
      yout[row * HH + h] = o;
    else if (t == TT - 1)
      yout[(long)v * HH + h] = o;
  }
}

// ---- final [V,64] @ [64,64] + b ----
__global__ __launch_bounds__(256) void final_kernel(const float* __restrict__ y, const float* __restrict__ W,
                                                    const float* __restrict__ b, float* __restrict__ out) {
  int idx = blockIdx.x * 256 + threadIdx.x;
  if (idx >= VV * CO) return;
  int j = idx & 63;
  int v = idx >> 6;
  float acc = b[j];
#pragma unroll
  for (int h = 0; h < HH; h++) acc = fmaf(y[v * HH + h], W[h * CO + j], acc);
  out[idx] = acc;
}

extern "C" void kernel_launch(void* const* d_in, const int* in_sizes, int n_in, void* d_out, int out_size,
                              void* d_ws, size_t ws_size, hipStream_t stream) {
  const float* xs = (const float*)d_in[0];
  const int* ei = (const int*)d_in[1];
  const float* Wl0 = (const float*)d_in[2];
  const float* Wr0 = (const float*)d_in[3];
  const float* bc0 = (const float*)d_in[4];
  const float* Wl1 = (const float*)d_in[5];
  const float* Wr1 = (const float*)d_in[6];
  const float* bc1 = (const float*)d_in[7];
  const float* Wres0 = (const float*)d_in[8];
  const float* bres0 = (const float*)d_in[9];
  const float* Wres1 = (const float*)d_in[10];
  const float* bres1 = (const float*)d_in[11];
  const float* tkw = (const float*)d_in[12];
  const float* tkb = (const float*)d_in[13];
  const float* logA = (const float*)d_in[14];
  const float* dlt = (const float*)d_in[15];
  const float* Wmlp = (const float*)d_in[16];
  const float* bmlp = (const float*)d_in[17];
  float* out = (float*)d_out;

  float* ws = (float*)d_ws;
  float* outs = ws;                  // R*160
  float* xsr = outs + (long)RR * 160;  // R*64
  float* x1 = xsr + (long)RR * 64;     // R*64 (layer-0 y; layer-1 final y)
  float* agg = x1 + (long)RR * 64;     // R*128
  int* cnt = (int*)(agg + (long)RR * 128);  // R
  int* off = cnt + RR;                      // R+1
  int* cursor = off + RR + 1;               // R
  int* bsum = cursor + RR;                  // 512
  int* csr = bsum + 512;                    // T*E = 1.28M

  const int NB = (RR + 255) / 256;  // 313 scan blocks

  // ---- CSR build (edges shared by both layers) ----
  hipMemsetAsync(cnt, 0, RR * sizeof(int), stream);
  count_kernel<<<(TT * EE + 255) / 256, 256, 0, stream>>>(ei, cnt);
  scan_block<<<NB, 256, 0, stream>>>(cnt, off, bsum);
  scan_tops<<<1, 512, 0, stream>>>(bsum, NB);
  scan_add<<<NB, 256, 0, stream>>>(off, bsum, cursor);
  scatter_kernel<<<(TT * EE + 255) / 256, 256, 0, stream>>>(ei, cursor, csr);

  // ---- layer 0 ----
  gather_kernel<128><<<RR / 2, 256, 0, stream>>>(off, csr, xs, agg);
  conv_fused<128><<<RR / 16, 256, 0, stream>>>(xs, agg, cnt, Wl0, Wr0, bc0, Wres0, bres0, outs, xsr);
  ssm_kernel<<<VV / 4, 256, 0, stream>>>(outs, xsr, logA, dlt, tkw, tkb, x1, 0);

  // ---- layer 1 ----
  gather_kernel<64><<<RR / 4, 256, 0, stream>>>(off, csr, x1, agg);
  conv_fused<64><<<RR / 16, 256, 0, stream>>>(x1, agg, cnt, Wl1, Wr1, bc1, Wres1, bres1, outs, xsr);
  ssm_kernel<<<VV / 4, 256, 0, stream>>>(outs, xsr, logA + HH * NN, dlt + HH, nullptr, nullptr, x1, 1);

  // ---- head ----
  final_kernel<<<(VV * CO) / 256, 256, 0, stream>>>(x1, Wmlp, bmlp, out);
}

// Round 3
// 697.918 us; speedup vs baseline: 5.4846x; 1.3388x over previous
//
#include <hip/hip_runtime.h>

#define TT 8
#define VV 10000
#define EE 160000
#define HH 64
#define NN 16
#define CO 64
#define NOUT 224  // 160 conv outs + 64 residual
#define RR (TT * VV)

typedef float f32x4 __attribute__((ext_vector_type(4)));
typedef __bf16 bf16x8 __attribute__((ext_vector_type(8)));

__device__ __forceinline__ unsigned short f2bf(float f) {
  union { float f; unsigned u; } v;
  v.f = f;
  unsigned r = v.u + 0x7fffu + ((v.u >> 16) & 1u);
  return (unsigned short)(r >> 16);
}
__device__ __forceinline__ float bf2f(unsigned short h) {
  union { unsigned u; float f; } v;
  v.u = ((unsigned)h) << 16;
  return v.f;
}

__device__ __forceinline__ float wave_sum64(float v) {
#pragma unroll
  for (int m = 32; m > 0; m >>= 1) v += __shfl_xor(v, m, 64);
  return v;
}

// ---- in-degree counts ----
__global__ __launch_bounds__(256) void count_kernel(const int* __restrict__ ei, int* __restrict__ cnt) {
  int idx = blockIdx.x * 256 + threadIdx.x;
  if (idx >= TT * EE) return;
  int t = idx / EE, e = idx - t * EE;
  int dst = ei[(t * 2 + 1) * EE + e];
  atomicAdd(&cnt[t * VV + dst], 1);
}

// ---- CSR build: block-level exclusive scan ----
__global__ __launch_bounds__(256) void scan_block(const int* __restrict__ cnt, int* __restrict__ off,
                                                  int* __restrict__ bsum) {
  __shared__ int sm[256];
  int i = blockIdx.x * 256 + threadIdx.x;
  int v = (i < RR) ? cnt[i] : 0;
  sm[threadIdx.x] = v;
  __syncthreads();
  for (int d = 1; d < 256; d <<= 1) {
    int t = (threadIdx.x >= d) ? sm[threadIdx.x - d] : 0;
    __syncthreads();
    sm[threadIdx.x] += t;
    __syncthreads();
  }
  if (i < RR) off[i] = sm[threadIdx.x] - v;
  if (threadIdx.x == 255) bsum[blockIdx.x] = sm[255];
}

__global__ __launch_bounds__(512) void scan_tops(int* __restrict__ bsum, int nb) {
  __shared__ int sm[512];
  int v = (threadIdx.x < nb) ? bsum[threadIdx.x] : 0;
  sm[threadIdx.x] = v;
  __syncthreads();
  for (int d = 1; d < 512; d <<= 1) {
    int t = (threadIdx.x >= d) ? sm[threadIdx.x - d] : 0;
    __syncthreads();
    sm[threadIdx.x] += t;
    __syncthreads();
  }
  if (threadIdx.x < nb) bsum[threadIdx.x] = sm[threadIdx.x] - v;
}

__global__ __launch_bounds__(256) void scan_add(int* __restrict__ off, const int* __restrict__ bsum,
                                                int* __restrict__ cursor) {
  int i = blockIdx.x * 256 + threadIdx.x;
  if (i < RR) {
    int o = off[i] + bsum[blockIdx.x];
    off[i] = o;
    cursor[i] = o;
  }
  if (i == 0) off[RR] = TT * EE;
}

__global__ __launch_bounds__(256) void scatter_kernel(const int* __restrict__ ei, int* __restrict__ cursor,
                                                      int* __restrict__ csr) {
  int idx = blockIdx.x * 256 + threadIdx.x;
  if (idx >= TT * EE) return;
  int t = idx / EE, e = idx - t * EE;
  int src = ei[(t * 2) * EE + e];
  int dst = ei[(t * 2 + 1) * EE + e];
  int pos = atomicAdd(&cursor[t * VV + dst], 1);
  csr[pos] = t * VV + src;
}

// ---- cast xs -> A_hi[:,0:128] (bf16 hi), A_lo[:,0:128] (bf16 lo) ----
__global__ __launch_bounds__(256) void cast_x0(const float* __restrict__ xs, unsigned short* __restrict__ Ahi,
                                               unsigned short* __restrict__ Alo) {
  int idx = blockIdx.x * 256 + threadIdx.x;  // one per float4, RR*32 total
  int row = idx >> 5, c4 = (idx & 31) * 4;
  float4 v = *reinterpret_cast<const float4*>(&xs[(long)row * 128 + c4]);
  ushort4 hs, ls;
  hs.x = f2bf(v.x); hs.y = f2bf(v.y); hs.z = f2bf(v.z); hs.w = f2bf(v.w);
  ls.x = f2bf(v.x - bf2f(hs.x)); ls.y = f2bf(v.y - bf2f(hs.y));
  ls.z = f2bf(v.z - bf2f(hs.z)); ls.w = f2bf(v.w - bf2f(hs.w));
  *reinterpret_cast<ushort4*>(&Ahi[(long)row * 256 + c4]) = hs;
  *reinterpret_cast<ushort4*>(&Alo[(long)row * 128 + c4]) = ls;
}

// ---- build stacked bf16 weight matrix Bp[n][k] (transposed, row stride Ktot) + bias ----
// k regions (size Cin each): 0:hi(Wl/Wres) 1:hi(Wr/0) 2:lo(Wl/Wres) 3:lo(Wr/0) 4:hi(Wl/Wres)
__global__ __launch_bounds__(256) void prep_b(const float* __restrict__ Wl, const float* __restrict__ Wr,
                                              const float* __restrict__ Wres, const float* __restrict__ bc,
                                              const float* __restrict__ bres, int Cin, int Ktot,
                                              unsigned short* __restrict__ Bp, float* __restrict__ bias) {
  int idx = blockIdx.x * 256 + threadIdx.x;
  if (idx >= NOUT * Ktot) return;
  int n = idx / Ktot, k = idx - n * Ktot;
  int reg = k / Cin, kk = k - reg * Cin;
  float w;
  if (reg == 1 || reg == 3)
    w = (n < 160) ? Wr[kk * 160 + n] : 0.f;
  else
    w = (n < 160) ? Wl[kk * 160 + n] : Wres[kk * 64 + (n - 160)];
  unsigned short h = f2bf(w);
  Bp[idx] = (reg == 2 || reg == 3) ? f2bf(w - bf2f(h)) : h;
  if (k == 0) bias[n] = (n < 160) ? bc[n] : bres[n - 160];
}

// ---- gather layer 0: mean over in-neighbors of fp32 xs -> bf16 hi into A_hi[:,128:256] ----
__global__ __launch_bounds__(256) void gather0(const int* __restrict__ off, const int* __restrict__ csr,
                                               const float* __restrict__ x, unsigned short* __restrict__ Ahi) {
  int grp = threadIdx.x >> 7;  // 2 rows per block
  int lane = threadIdx.x & 127;
  int row = blockIdx.x * 2 + grp;
  int s = off[row], e = off[row + 1];
  float acc = 0.f;
  for (int i = s; i < e; i++) acc += x[(long)csr[i] * 128 + lane];
  float m = acc / (float)max(e - s, 1);
  Ahi[(long)row * 256 + 128 + lane] = f2bf(m);
}

// ---- gather layer 1: x1 stored as bf16 hi+lo in A buffers; mean -> A_hi[:,64:128] ----
__global__ __launch_bounds__(256) void gather1(const int* __restrict__ off, const int* __restrict__ csr,
                                               const unsigned short* __restrict__ Ahi_in,
                                               const unsigned short* __restrict__ Alo_in,
                                               unsigned short* __restrict__ Ahi) {
  int grp = threadIdx.x >> 6;  // 4 rows per block
  int lane = threadIdx.x & 63;
  int row = blockIdx.x * 4 + grp;
  int s = off[row], e = off[row + 1];
  float acc = 0.f;
  for (int i = s; i < e; i++) {
    long g = csr[i];
    acc += bf2f(Ahi_in[g * 256 + lane]) + bf2f(Alo_in[g * 128 + lane]);
  }
  float m = acc / (float)max(e - s, 1);
  Ahi[(long)row * 256 + 64 + lane] = f2bf(m);
}

// ---- bf16x3 MFMA GEMM: outs[80000 x 224] = A' @ Bp + bias ----
// A' k-tiles map to A_hi (twice) then A_lo per sw1/sw2 thresholds.
__global__ __launch_bounds__(256) void gemm_kernel(const unsigned short* __restrict__ Ahi,
                                                   const unsigned short* __restrict__ Alo,
                                                   const unsigned short* __restrict__ Bp,
                                                   const float* __restrict__ bias, float* __restrict__ outs,
                                                   int Ktot, int sw1, int sw2, int lda, int ldalo) {
  __shared__ unsigned short As[128][72];  // +8 pad kills bank conflicts
  __shared__ unsigned short Bs[224][72];
  int tid = threadIdx.x;
  long row0 = (long)blockIdx.x * 128;
  int wid = tid >> 6, lane = tid & 63;
  int wr = wid & 1, wc = wid >> 1;  // wave = 64 rows x 112 cols
  int l15 = lane & 15, lg = lane >> 4;
  f32x4 acc[4][7];
#pragma unroll
  for (int i = 0; i < 4; i++)
#pragma unroll
    for (int n = 0; n < 7; n++) acc[i][n] = (f32x4)(0.f);
  int ar = tid >> 1, ah = tid & 1;  // A staging: row, 32-elem half
  int nt = Ktot / 64;
  for (int kt = 0; kt < nt; kt++) {
    int k0 = kt * 64;
    const unsigned short* asrc;
    int astr;
    if (k0 < sw1) {
      asrc = Ahi + k0;
      astr = lda;
    } else if (k0 < sw2) {
      asrc = Ahi + (k0 - sw1);
      astr = lda;
    } else {
      asrc = Alo + (k0 - sw2);
      astr = ldalo;
    }
    const int4* ag = reinterpret_cast<const int4*>(asrc + (row0 + ar) * (long)astr + ah * 32);
    int4 av0 = ag[0], av1 = ag[1], av2 = ag[2], av3 = ag[3];
    int4 bv0, bv1, bv2, bv3, bv4, bv5, bv6, bv7;
    if (tid < 224) {
      const int4* bg = reinterpret_cast<const int4*>(Bp + (long)tid * Ktot + k0);
      bv0 = bg[0]; bv1 = bg[1]; bv2 = bg[2]; bv3 = bg[3];
      bv4 = bg[4]; bv5 = bg[5]; bv6 = bg[6]; bv7 = bg[7];
    }
    __syncthreads();  // previous iteration's LDS reads complete
    {
      int4* aw = reinterpret_cast<int4*>(&As[ar][ah * 32]);
      aw[0] = av0; aw[1] = av1; aw[2] = av2; aw[3] = av3;
      if (tid < 224) {
        int4* bw = reinterpret_cast<int4*>(&Bs[tid][0]);
        bw[0] = bv0; bw[1] = bv1; bw[2] = bv2; bw[3] = bv3;
        bw[4] = bv4; bw[5] = bv5; bw[6] = bv6; bw[7] = bv7;
      }
    }
    __syncthreads();
#pragma unroll
    for (int kk = 0; kk < 2; kk++) {
      bf16x8 af[4];
#pragma unroll
      for (int i = 0; i < 4; i++)
        af[i] = *reinterpret_cast<const bf16x8*>(&As[wr * 64 + i * 16 + l15][kk * 32 + lg * 8]);
#pragma unroll
      for (int n = 0; n < 7; n++) {
        bf16x8 bfr = *reinterpret_cast<const bf16x8*>(&Bs[wc * 112 + n * 16 + l15][kk * 32 + lg * 8]);
#pragma unroll
        for (int i = 0; i < 4; i++)
          acc[i][n] = __builtin_amdgcn_mfma_f32_16x16x32_bf16(af[i], bfr, acc[i][n], 0, 0, 0);
      }
    }
  }
#pragma unroll
  for (int i = 0; i < 4; i++) {
    long grow = row0 + wr * 64 + i * 16 + lg * 4;
#pragma unroll
    for (int n = 0; n < 7; n++) {
      int gcol = wc * 112 + n * 16 + l15;
      float bv = bias[gcol];
#pragma unroll
      for (int r = 0; r < 4; r++) outs[(grow + r) * NOUT + gcol] = acc[i][n][r] + bv;
    }
  }
}

// ---- diagonal SSM scan over T (token-mix inlined for layer 0) ----
// outs row layout: [xh(64) | dts(64) | Bs(16) | Cs(16) | xsr(64)]
__global__ __launch_bounds__(256) void ssm_kernel(const float* __restrict__ outs, const float* __restrict__ logA,
                                                  const float* __restrict__ dlt, const float* __restrict__ tkw,
                                                  const float* __restrict__ tkb, unsigned short* __restrict__ xhi,
                                                  unsigned short* __restrict__ xlo, float* __restrict__ yfin,
                                                  int mode /*0: tkmix, write bf16 all T; 1: write last T fp32*/) {
  int v = blockIdx.x * 4 + (threadIdx.x >> 6);
  int h = threadIdx.x & 63;
  float A[NN], s[NN];
#pragma unroll
  for (int n = 0; n < NN; n++) {
    A[n] = -__expf(logA[h * NN + n]);
    s[n] = 0.f;
  }
  float dh = dlt[h];
  float w0 = 0.f, w1 = 0.f, w2 = 0.f, tb = 0.f;
  float xhm = 0.f, xh0 = 0.f;
  if (mode == 0) {
    w0 = tkw[h * 3 + 0];
    w1 = tkw[h * 3 + 1];
    w2 = tkw[h * 3 + 2];
    tb = tkb[h];
    xh0 = outs[(long)v * NOUT + h];
  }
  for (int t = 0; t < TT; t++) {
    long row = (long)t * VV + v;
    float dtr = outs[row * NOUT + HH + h] + dh;
    float dt = dtr > 20.f ? dtr : log1pf(__expf(dtr));
    float xv;
    if (mode == 0) {
      float xh1 = (t < TT - 1) ? outs[(row + VV) * NOUT + h] : 0.f;
      xv = fmaf(xhm, w0, fmaf(xh0, w1, fmaf(xh1, w2, tb)));
      xhm = xh0;
      xh0 = xh1;
    } else {
      xv = outs[row * NOUT + h];
    }
    float r = outs[row * NOUT + 160 + h];
    float y = 0.f;
#pragma unroll
    for (int n = 0; n < NN; n++) {
      float Bn = outs[row * NOUT + 2 * HH + n];
      float Cn = outs[row * NOUT + 2 * HH + NN + n];
      s[n] = fmaf(__expf(dt * A[n]), s[n], dt * Bn * xv);
      y = fmaf(s[n], Cn, y);
    }
    y = fmaxf(y, 0.f);
    float z = y + r;
    float m = wave_sum64(z) * (1.f / 64.f);
    float d = z - m;
    float var = wave_sum64(d * d) * (1.f / 64.f);
    float o = d * rsqrtf(var + 1e-5f);
    if (mode == 0) {
      unsigned short hi = f2bf(o);
      xhi[row * 256 + h] = hi;
      xlo[row * 128 + h] = f2bf(o - bf2f(hi));
    } else if (t == TT - 1) {
      yfin[(long)v * HH + h] = o;
    }
  }
}

// ---- final [V,64] @ [64,64] + b ----
__global__ __launch_bounds__(256) void final_kernel(const float* __restrict__ y, const float* __restrict__ W,
                                                    const float* __restrict__ b, float* __restrict__ out) {
  int idx = blockIdx.x * 256 + threadIdx.x;
  if (idx >= VV * CO) return;
  int j = idx & 63;
  int v = idx >> 6;
  float acc = b[j];
#pragma unroll
  for (int h = 0; h < HH; h++) acc = fmaf(y[v * HH + h], W[h * CO + j], acc);
  out[idx] = acc;
}

extern "C" void kernel_launch(void* const* d_in, const int* in_sizes, int n_in, void* d_out, int out_size,
                              void* d_ws, size_t ws_size, hipStream_t stream) {
  const float* xs = (const float*)d_in[0];
  const int* ei = (const int*)d_in[1];
  const float* Wl0 = (const float*)d_in[2];
  const float* Wr0 = (const float*)d_in[3];
  const float* bc0 = (const float*)d_in[4];
  const float* Wl1 = (const float*)d_in[5];
  const float* Wr1 = (const float*)d_in[6];
  const float* bc1 = (const float*)d_in[7];
  const float* Wres0 = (const float*)d_in[8];
  const float* bres0 = (const float*)d_in[9];
  const float* Wres1 = (const float*)d_in[10];
  const float* bres1 = (const float*)d_in[11];
  const float* tkw = (const float*)d_in[12];
  const float* tkb = (const float*)d_in[13];
  const float* logA = (const float*)d_in[14];
  const float* dlt = (const float*)d_in[15];
  const float* Wmlp = (const float*)d_in[16];
  const float* bmlp = (const float*)d_in[17];
  float* out = (float*)d_out;

  float* outs = (float*)d_ws;                          // RR*224 f32
  unsigned short* Ahi = (unsigned short*)(outs + (long)RR * NOUT);  // RR*256 bf16
  unsigned short* Alo = Ahi + (long)RR * 256;          // RR*128 bf16
  unsigned short* Bp0 = Alo + (long)RR * 128;          // 224*640
  unsigned short* Bp1 = Bp0 + 224 * 640;               // 224*320
  float* bias0 = (float*)(Bp1 + 224 * 320);            // 224
  float* bias1 = bias0 + 224;                          // 224
  float* yfin = bias1 + 224;                           // VV*64
  int* cnt = (int*)(yfin + (long)VV * 64);             // RR
  int* off = cnt + RR;                                 // RR+1
  int* cursor = off + RR + 1;                          // RR
  int* bsum = cursor + RR;                             // 512
  int* csr = bsum + 512;                               // TT*EE

  const int NB = (RR + 255) / 256;

  // ---- CSR build (edges shared by both layers) ----
  hipMemsetAsync(cnt, 0, RR * sizeof(int), stream);
  count_kernel<<<(TT * EE + 255) / 256, 256, 0, stream>>>(ei, cnt);
  scan_block<<<NB, 256, 0, stream>>>(cnt, off, bsum);
  scan_tops<<<1, 512, 0, stream>>>(bsum, NB);
  scan_add<<<NB, 256, 0, stream>>>(off, bsum, cursor);
  scatter_kernel<<<(TT * EE + 255) / 256, 256, 0, stream>>>(ei, cursor, csr);

  // ---- weight prep ----
  prep_b<<<(NOUT * 640 + 255) / 256, 256, 0, stream>>>(Wl0, Wr0, Wres0, bc0, bres0, 128, 640, Bp0, bias0);
  prep_b<<<(NOUT * 320 + 255) / 256, 256, 0, stream>>>(Wl1, Wr1, Wres1, bc1, bres1, 64, 320, Bp1, bias1);

  // ---- layer 0 ----
  cast_x0<<<RR * 32 / 256, 256, 0, stream>>>(xs, Ahi, Alo);
  gather0<<<RR / 2, 256, 0, stream>>>(off, csr, xs, Ahi);
  gemm_kernel<<<RR / 128, 256, 0, stream>>>(Ahi, Alo, Bp0, bias0, outs, 640, 256, 512, 256, 128);
  ssm_kernel<<<VV / 4, 256, 0, stream>>>(outs, logA, dlt, tkw, tkb, Ahi, Alo, nullptr, 0);

  // ---- layer 1 ----
  gather1<<<RR / 4, 256, 0, stream>>>(off, csr, Ahi, Alo, Ahi);
  gemm_kernel<<<RR / 128, 256, 0, stream>>>(Ahi, Alo, Bp1, bias1, outs, 320, 128, 256, 256, 128);
  ssm_kernel<<<VV / 4, 256, 0, stream>>>(outs, logA + HH * NN, dlt + HH, nullptr, nullptr, nullptr, nullptr, yfin, 1);

  // ---- head ----
  final_kernel<<<(VV * CO) / 256, 256, 0, stream>>>(yfin, Wmlp, bmlp, out);
}

// Round 4
// 463.209 us; speedup vs baseline: 8.2636x; 1.5067x over previous
//
#include <hip/hip_runtime.h>

#define TT 8
#define VV 10000
#define EE 160000
#define HH 64
#define NN 16
#define CO 64
#define NOUT 224  // 160 conv outs + 64 residual
#define RR (TT * VV)

typedef float f32x4 __attribute__((ext_vector_type(4)));
typedef __bf16 bf16x8 __attribute__((ext_vector_type(8)));
typedef unsigned int uint;

__device__ __forceinline__ unsigned short f2bf(float f) {
  union { float f; unsigned u; } v;
  v.f = f;
  unsigned r = v.u + 0x7fffu + ((v.u >> 16) & 1u);
  return (unsigned short)(r >> 16);
}
__device__ __forceinline__ float bf2f(unsigned h) {
  union { unsigned u; float f; } v;
  v.u = h << 16;
  return v.f;
}

__device__ __forceinline__ float wave_sum64(float v) {
#pragma unroll
  for (int m = 32; m > 0; m >>= 1) v += __shfl_xor(v, m, 64);
  return v;
}

// ---- in-degree counts ----
__global__ __launch_bounds__(256) void count_kernel(const int* __restrict__ ei, int* __restrict__ cnt) {
  int idx = blockIdx.x * 256 + threadIdx.x;
  if (idx >= TT * EE) return;
  int t = idx / EE, e = idx - t * EE;
  int dst = ei[(t * 2 + 1) * EE + e];
  atomicAdd(&cnt[t * VV + dst], 1);
}

// ---- CSR build: block-level exclusive scan ----
__global__ __launch_bounds__(256) void scan_block(const int* __restrict__ cnt, int* __restrict__ off,
                                                  int* __restrict__ bsum) {
  __shared__ int sm[256];
  int i = blockIdx.x * 256 + threadIdx.x;
  int v = (i < RR) ? cnt[i] : 0;
  sm[threadIdx.x] = v;
  __syncthreads();
  for (int d = 1; d < 256; d <<= 1) {
    int t = (threadIdx.x >= d) ? sm[threadIdx.x - d] : 0;
    __syncthreads();
    sm[threadIdx.x] += t;
    __syncthreads();
  }
  if (i < RR) off[i] = sm[threadIdx.x] - v;
  if (threadIdx.x == 255) bsum[blockIdx.x] = sm[255];
}

__global__ __launch_bounds__(512) void scan_tops(int* __restrict__ bsum, int nb) {
  __shared__ int sm[512];
  int v = (threadIdx.x < nb) ? bsum[threadIdx.x] : 0;
  sm[threadIdx.x] = v;
  __syncthreads();
  for (int d = 1; d < 512; d <<= 1) {
    int t = (threadIdx.x >= d) ? sm[threadIdx.x - d] : 0;
    __syncthreads();
    sm[threadIdx.x] += t;
    __syncthreads();
  }
  if (threadIdx.x < nb) bsum[threadIdx.x] = sm[threadIdx.x] - v;
}

__global__ __launch_bounds__(256) void scan_add(int* __restrict__ off, const int* __restrict__ bsum,
                                                int* __restrict__ cursor) {
  int i = blockIdx.x * 256 + threadIdx.x;
  if (i < RR) {
    int o = off[i] + bsum[blockIdx.x];
    off[i] = o;
    cursor[i] = o;
  }
  if (i == 0) off[RR] = TT * EE;
}

__global__ __launch_bounds__(256) void scatter_kernel(const int* __restrict__ ei, int* __restrict__ cursor,
                                                      int* __restrict__ csr) {
  int idx = blockIdx.x * 256 + threadIdx.x;
  if (idx >= TT * EE) return;
  int t = idx / EE, e = idx - t * EE;
  int src = ei[(t * 2) * EE + e];
  int dst = ei[(t * 2 + 1) * EE + e];
  int pos = atomicAdd(&cursor[t * VV + dst], 1);
  csr[pos] = t * VV + src;
}

// ---- cast xs -> A_hi[:,0:128] (bf16 hi), A_lo[:,0:128] (bf16 lo) ----
__global__ __launch_bounds__(256) void cast_x0(const float* __restrict__ xs, unsigned short* __restrict__ Ahi,
                                               unsigned short* __restrict__ Alo) {
  int idx = blockIdx.x * 256 + threadIdx.x;  // one per float4, RR*32 total
  int row = idx >> 5, c4 = (idx & 31) * 4;
  float4 v = *reinterpret_cast<const float4*>(&xs[(long)row * 128 + c4]);
  ushort4 hs, ls;
  hs.x = f2bf(v.x); hs.y = f2bf(v.y); hs.z = f2bf(v.z); hs.w = f2bf(v.w);
  ls.x = f2bf(v.x - bf2f(hs.x)); ls.y = f2bf(v.y - bf2f(hs.y));
  ls.z = f2bf(v.z - bf2f(hs.z)); ls.w = f2bf(v.w - bf2f(hs.w));
  *reinterpret_cast<ushort4*>(&Ahi[(long)row * 256 + c4]) = hs;
  *reinterpret_cast<ushort4*>(&Alo[(long)row * 128 + c4]) = ls;
}

// ---- build stacked bf16 weight matrix Bp[n][k] (transposed, row stride Ktot) + bias ----
// k regions (size Cin each): 0:hi(Wl/Wres) 1:hi(Wr/0) 2:lo(Wl/Wres) 3:lo(Wr/0) 4:hi(Wl/Wres)
__global__ __launch_bounds__(256) void prep_b(const float* __restrict__ Wl, const float* __restrict__ Wr,
                                              const float* __restrict__ Wres, const float* __restrict__ bc,
                                              const float* __restrict__ bres, int Cin, int Ktot,
                                              unsigned short* __restrict__ Bp, float* __restrict__ bias) {
  int idx = blockIdx.x * 256 + threadIdx.x;
  if (idx >= NOUT * Ktot) return;
  int n = idx / Ktot, k = idx - n * Ktot;
  int reg = k / Cin, kk = k - reg * Cin;
  float w;
  if (reg == 1 || reg == 3)
    w = (n < 160) ? Wr[kk * 160 + n] : 0.f;
  else
    w = (n < 160) ? Wl[kk * 160 + n] : Wres[kk * 64 + (n - 160)];
  unsigned short h = f2bf(w);
  Bp[idx] = (reg == 2 || reg == 3) ? f2bf(w - bf2f(h)) : h;
  if (k == 0) bias[n] = (n < 160) ? bc[n] : bres[n - 160];
}

// ---- gather layer 0 (latency-optimized): mean of bf16-hi rows, 1 wave per row ----
// Xhi viewed as uint (2 channels per load); writes packed mean-hi to cols 128:256.
__global__ __launch_bounds__(256) void gather0(const int* __restrict__ off, const int* __restrict__ csr,
                                               const uint* __restrict__ Xhi, uint* __restrict__ Mout) {
  int w = threadIdx.x >> 6;
  int lane = threadIdx.x & 63;
  int row = blockIdx.x * 4 + w;
  int s = off[row], e = off[row + 1];
  float a0 = 0.f, a1 = 0.f;
  int i = s;
  for (; i + 4 <= e; i += 4) {
    int g0 = csr[i], g1 = csr[i + 1], g2 = csr[i + 2], g3 = csr[i + 3];
    uint w0 = Xhi[(long)g0 * 128 + lane];
    uint w1 = Xhi[(long)g1 * 128 + lane];
    uint w2 = Xhi[(long)g2 * 128 + lane];
    uint w3 = Xhi[(long)g3 * 128 + lane];
    a0 += bf2f(w0 & 0xffffu) + bf2f(w1 & 0xffffu) + bf2f(w2 & 0xffffu) + bf2f(w3 & 0xffffu);
    a1 += bf2f(w0 >> 16) + bf2f(w1 >> 16) + bf2f(w2 >> 16) + bf2f(w3 >> 16);
  }
  for (; i < e; i++) {
    uint w0 = Xhi[(long)csr[i] * 128 + lane];
    a0 += bf2f(w0 & 0xffffu);
    a1 += bf2f(w0 >> 16);
  }
  float inv = 1.f / (float)max(e - s, 1);
  uint hp = (uint)f2bf(a0 * inv) | ((uint)f2bf(a1 * inv) << 16);
  Mout[(long)row * 128 + 64 + lane] = hp;
}

// ---- gather layer 1: 2 rows per wave (32 lane-pairs each), mean-hi -> cols 64:128 ----
__global__ __launch_bounds__(256) void gather1(const int* __restrict__ off, const int* __restrict__ csr,
                                               const uint* __restrict__ Xhi, uint* __restrict__ Mout) {
  int w = threadIdx.x >> 6;
  int lane = threadIdx.x & 63;
  int sub = lane >> 5;
  int p = lane & 31;
  int row = blockIdx.x * 8 + w * 2 + sub;
  int s = off[row], e = off[row + 1];
  float a0 = 0.f, a1 = 0.f;
  int i = s;
  for (; i + 4 <= e; i += 4) {
    int g0 = csr[i], g1 = csr[i + 1], g2 = csr[i + 2], g3 = csr[i + 3];
    uint w0 = Xhi[(long)g0 * 128 + p];
    uint w1 = Xhi[(long)g1 * 128 + p];
    uint w2 = Xhi[(long)g2 * 128 + p];
    uint w3 = Xhi[(long)g3 * 128 + p];
    a0 += bf2f(w0 & 0xffffu) + bf2f(w1 & 0xffffu) + bf2f(w2 & 0xffffu) + bf2f(w3 & 0xffffu);
    a1 += bf2f(w0 >> 16) + bf2f(w1 >> 16) + bf2f(w2 >> 16) + bf2f(w3 >> 16);
  }
  for (; i < e; i++) {
    uint w0 = Xhi[(long)csr[i] * 128 + p];
    a0 += bf2f(w0 & 0xffffu);
    a1 += bf2f(w0 >> 16);
  }
  float inv = 1.f / (float)max(e - s, 1);
  uint hp = (uint)f2bf(a0 * inv) | ((uint)f2bf(a1 * inv) << 16);
  Mout[(long)row * 128 + 32 + p] = hp;
}

// ---- bf16x3 MFMA GEMM: outs[80000 x 224] = A' @ Bp + bias ----
__global__ __launch_bounds__(256) void gemm_kernel(const unsigned short* __restrict__ Ahi,
                                                   const unsigned short* __restrict__ Alo,
                                                   const unsigned short* __restrict__ Bp,
                                                   const float* __restrict__ bias, float* __restrict__ outs,
                                                   int Ktot, int sw1, int sw2, int lda, int ldalo) {
  __shared__ unsigned short As[128][72];  // +8 pad kills bank conflicts
  __shared__ unsigned short Bs[224][72];
  int tid = threadIdx.x;
  long row0 = (long)blockIdx.x * 128;
  int wid = tid >> 6, lane = tid & 63;
  int wr = wid & 1, wc = wid >> 1;  // wave = 64 rows x 112 cols
  int l15 = lane & 15, lg = lane >> 4;
  f32x4 acc[4][7];
#pragma unroll
  for (int i = 0; i < 4; i++)
#pragma unroll
    for (int n = 0; n < 7; n++) acc[i][n] = (f32x4)(0.f);
  int ar = tid >> 1, ah = tid & 1;  // A staging: row, 32-elem half
  int nt = Ktot / 64;
  for (int kt = 0; kt < nt; kt++) {
    int k0 = kt * 64;
    const unsigned short* asrc;
    int astr;
    if (k0 < sw1) {
      asrc = Ahi + k0;
      astr = lda;
    } else if (k0 < sw2) {
      asrc = Ahi + (k0 - sw1);
      astr = lda;
    } else {
      asrc = Alo + (k0 - sw2);
      astr = ldalo;
    }
    const int4* ag = reinterpret_cast<const int4*>(asrc + (row0 + ar) * (long)astr + ah * 32);
    int4 av0 = ag[0], av1 = ag[1], av2 = ag[2], av3 = ag[3];
    int4 bv0, bv1, bv2, bv3, bv4, bv5, bv6, bv7;
    if (tid < 224) {
      const int4* bg = reinterpret_cast<const int4*>(Bp + (long)tid * Ktot + k0);
      bv0 = bg[0]; bv1 = bg[1]; bv2 = bg[2]; bv3 = bg[3];
      bv4 = bg[4]; bv5 = bg[5]; bv6 = bg[6]; bv7 = bg[7];
    }
    __syncthreads();  // previous iteration's LDS reads complete
    {
      int4* aw = reinterpret_cast<int4*>(&As[ar][ah * 32]);
      aw[0] = av0; aw[1] = av1; aw[2] = av2; aw[3] = av3;
      if (tid < 224) {
        int4* bw = reinterpret_cast<int4*>(&Bs[tid][0]);
        bw[0] = bv0; bw[1] = bv1; bw[2] = bv2; bw[3] = bv3;
        bw[4] = bv4; bw[5] = bv5; bw[6] = bv6; bw[7] = bv7;
      }
    }
    __syncthreads();
#pragma unroll
    for (int kk = 0; kk < 2; kk++) {
      bf16x8 af[4];
#pragma unroll
      for (int i = 0; i < 4; i++)
        af[i] = *reinterpret_cast<const bf16x8*>(&As[wr * 64 + i * 16 + l15][kk * 32 + lg * 8]);
#pragma unroll
      for (int n = 0; n < 7; n++) {
        bf16x8 bfr = *reinterpret_cast<const bf16x8*>(&Bs[wc * 112 + n * 16 + l15][kk * 32 + lg * 8]);
#pragma unroll
        for (int i = 0; i < 4; i++)
          acc[i][n] = __builtin_amdgcn_mfma_f32_16x16x32_bf16(af[i], bfr, acc[i][n], 0, 0, 0);
      }
    }
  }
#pragma unroll
  for (int i = 0; i < 4; i++) {
    long grow = row0 + wr * 64 + i * 16 + lg * 4;
#pragma unroll
    for (int n = 0; n < 7; n++) {
      int gcol = wc * 112 + n * 16 + l15;
      float bv = bias[gcol];
#pragma unroll
      for (int r = 0; r < 4; r++) outs[(grow + r) * NOUT + gcol] = acc[i][n][r] + bv;
    }
  }
}

// ---- diagonal SSM scan over T (token-mix inlined for layer 0) ----
// outs row layout: [xh(64) | dts(64) | Bs(16) | Cs(16) | xsr(64)]
__global__ __launch_bounds__(256) void ssm_kernel(const float* __restrict__ outs, const float* __restrict__ logA,
                                                  const float* __restrict__ dlt, const float* __restrict__ tkw,
                                                  const float* __restrict__ tkb, unsigned short* __restrict__ xhi,
                                                  unsigned short* __restrict__ xlo, float* __restrict__ yfin,
                                                  int mode /*0: tkmix, write bf16 all T; 1: write last T fp32*/) {
  int v = blockIdx.x * 4 + (threadIdx.x >> 6);
  int h = threadIdx.x & 63;
  float A[NN], s[NN];
#pragma unroll
  for (int n = 0; n < NN; n++) {
    A[n] = -__expf(logA[h * NN + n]);
    s[n] = 0.f;
  }
  float dh = dlt[h];
  float w0 = 0.f, w1 = 0.f, w2 = 0.f, tb = 0.f;
  float xhm = 0.f, xh0 = 0.f;
  if (mode == 0) {
    w0 = tkw[h * 3 + 0];
    w1 = tkw[h * 3 + 1];
    w2 = tkw[h * 3 + 2];
    tb = tkb[h];
    xh0 = outs[(long)v * NOUT + h];
  }
  for (int t = 0; t < TT; t++) {
    long row = (long)t * VV + v;
    float dtr = outs[row * NOUT + HH + h] + dh;
    float dt = dtr > 20.f ? dtr : log1pf(__expf(dtr));
    float xv;
    if (mode == 0) {
      float xh1 = (t < TT - 1) ? outs[(row + VV) * NOUT + h] : 0.f;
      xv = fmaf(xhm, w0, fmaf(xh0, w1, fmaf(xh1, w2, tb)));
      xhm = xh0;
      xh0 = xh1;
    } else {
      xv = outs[row * NOUT + h];
    }
    float r = outs[row * NOUT + 160 + h];
    float y = 0.f;
#pragma unroll
    for (int n = 0; n < NN; n++) {
      float Bn = outs[row * NOUT + 2 * HH + n];
      float Cn = outs[row * NOUT + 2 * HH + NN + n];
      s[n] = fmaf(__expf(dt * A[n]), s[n], dt * Bn * xv);
      y = fmaf(s[n], Cn, y);
    }
    y = fmaxf(y, 0.f);
    float z = y + r;
    float m = wave_sum64(z) * (1.f / 64.f);
    float d = z - m;
    float var = wave_sum64(d * d) * (1.f / 64.f);
    float o = d * rsqrtf(var + 1e-5f);
    if (mode == 0) {
      unsigned short hi = f2bf(o);
      xhi[row * 256 + h] = hi;
      xlo[row * 128 + h] = f2bf(o - bf2f(hi));
    } else if (t == TT - 1) {
      yfin[(long)v * HH + h] = o;
    }
  }
}

// ---- final [V,64] @ [64,64] + b ----
__global__ __launch_bounds__(256) void final_kernel(const float* __restrict__ y, const float* __restrict__ W,
                                                    const float* __restrict__ b, float* __restrict__ out) {
  int idx = blockIdx.x * 256 + threadIdx.x;
  if (idx >= VV * CO) return;
  int j = idx & 63;
  int v = idx >> 6;
  float acc = b[j];
#pragma unroll
  for (int h = 0; h < HH; h++) acc = fmaf(y[v * HH + h], W[h * CO + j], acc);
  out[idx] = acc;
}

extern "C" void kernel_launch(void* const* d_in, const int* in_sizes, int n_in, void* d_out, int out_size,
                              void* d_ws, size_t ws_size, hipStream_t stream) {
  const float* xs = (const float*)d_in[0];
  const int* ei = (const int*)d_in[1];
  const float* Wl0 = (const float*)d_in[2];
  const float* Wr0 = (const float*)d_in[3];
  const float* bc0 = (const float*)d_in[4];
  const float* Wl1 = (const float*)d_in[5];
  const float* Wr1 = (const float*)d_in[6];
  const float* bc1 = (const float*)d_in[7];
  const float* Wres0 = (const float*)d_in[8];
  const float* bres0 = (const float*)d_in[9];
  const float* Wres1 = (const float*)d_in[10];
  const float* bres1 = (const float*)d_in[11];
  const float* tkw = (const float*)d_in[12];
  const float* tkb = (const float*)d_in[13];
  const float* logA = (const float*)d_in[14];
  const float* dlt = (const float*)d_in[15];
  const float* Wmlp = (const float*)d_in[16];
  const float* bmlp = (const float*)d_in[17];
  float* out = (float*)d_out;

  float* outs = (float*)d_ws;                          // RR*224 f32
  unsigned short* Ahi = (unsigned short*)(outs + (long)RR * NOUT);  // RR*256 bf16
  unsigned short* Alo = Ahi + (long)RR * 256;          // RR*128 bf16
  unsigned short* Bp0 = Alo + (long)RR * 128;          // 224*640
  unsigned short* Bp1 = Bp0 + 224 * 640;               // 224*320
  float* bias0 = (float*)(Bp1 + 224 * 320);            // 224
  float* bias1 = bias0 + 224;                          // 224
  float* yfin = bias1 + 224;                           // VV*64
  int* cnt = (int*)(yfin + (long)VV * 64);             // RR
  int* off = cnt + RR;                                 // RR+1
  int* cursor = off + RR + 1;                          // RR
  int* bsum = cursor + RR;                             // 512
  int* csr = bsum + 512;                               // TT*EE

  const int NB = (RR + 255) / 256;

  // ---- CSR build (edges shared by both layers) ----
  hipMemsetAsync(cnt, 0, RR * sizeof(int), stream);
  count_kernel<<<(TT * EE + 255) / 256, 256, 0, stream>>>(ei, cnt);
  scan_block<<<NB, 256, 0, stream>>>(cnt, off, bsum);
  scan_tops<<<1, 512, 0, stream>>>(bsum, NB);
  scan_add<<<NB, 256, 0, stream>>>(off, bsum, cursor);
  scatter_kernel<<<(TT * EE + 255) / 256, 256, 0, stream>>>(ei, cursor, csr);

  // ---- weight prep ----
  prep_b<<<(NOUT * 640 + 255) / 256, 256, 0, stream>>>(Wl0, Wr0, Wres0, bc0, bres0, 128, 640, Bp0, bias0);
  prep_b<<<(NOUT * 320 + 255) / 256, 256, 0, stream>>>(Wl1, Wr1, Wres1, bc1, bres1, 64, 320, Bp1, bias1);

  // ---- layer 0 ----
  cast_x0<<<RR * 32 / 256, 256, 0, stream>>>(xs, Ahi, Alo);
  gather0<<<RR / 4, 256, 0, stream>>>(off, csr, (const uint*)Ahi, (uint*)Ahi);
  gemm_kernel<<<RR / 128, 256, 0, stream>>>(Ahi, Alo, Bp0, bias0, outs, 640, 256, 512, 256, 128);
  ssm_kernel<<<VV / 4, 256, 0, stream>>>(outs, logA, dlt, tkw, tkb, Ahi, Alo, nullptr, 0);

  // ---- layer 1 ----
  gather1<<<RR / 8, 256, 0, stream>>>(off, csr, (const uint*)Ahi, (uint*)Ahi);
  gemm_kernel<<<RR / 128, 256, 0, stream>>>(Ahi, Alo, Bp1, bias1, outs, 320, 128, 256, 256, 128);
  ssm_kernel<<<VV / 4, 256, 0, stream>>>(outs, logA + HH * NN, dlt + HH, nullptr, nullptr, nullptr, nullptr, yfin, 1);

  // ---- head ----
  final_kernel<<<(VV * CO) / 256, 256, 0, stream>>>(yfin, Wmlp, bmlp, out);
}

// Round 5
// 417.330 us; speedup vs baseline: 9.1720x; 1.1099x over previous
//
#include <hip/hip_runtime.h>

#define TT 8
#define VV 10000
#define EE 160000
#define HH 64
#define NN 16
#define CO 64
#define NOUT 224  // 160 conv outs + 64 residual
#define RR (TT * VV)

typedef float f32x4 __attribute__((ext_vector_type(4)));
typedef __bf16 bf16x8 __attribute__((ext_vector_type(8)));
typedef unsigned int uint;

#define GLOBAL_AS __attribute__((address_space(1)))
#define LDS_AS __attribute__((address_space(3)))

__device__ __forceinline__ unsigned short f2bf(float f) {
  union { float f; unsigned u; } v;
  v.f = f;
  unsigned r = v.u + 0x7fffu + ((v.u >> 16) & 1u);
  return (unsigned short)(r >> 16);
}
__device__ __forceinline__ float bf2f(unsigned h) {
  union { unsigned u; float f; } v;
  v.u = h << 16;
  return v.f;
}

__device__ __forceinline__ float wave_sum64(float v) {
#pragma unroll
  for (int m = 32; m > 0; m >>= 1) v += __shfl_xor(v, m, 64);
  return v;
}

// ---- in-degree counts ----
__global__ __launch_bounds__(256) void count_kernel(const int* __restrict__ ei, int* __restrict__ cnt) {
  int idx = blockIdx.x * 256 + threadIdx.x;
  if (idx >= TT * EE) return;
  int t = idx / EE, e = idx - t * EE;
  int dst = ei[(t * 2 + 1) * EE + e];
  atomicAdd(&cnt[t * VV + dst], 1);
}

// ---- CSR build: block-level exclusive scan ----
__global__ __launch_bounds__(256) void scan_block(const int* __restrict__ cnt, int* __restrict__ off,
                                                  int* __restrict__ bsum) {
  __shared__ int sm[256];
  int i = blockIdx.x * 256 + threadIdx.x;
  int v = (i < RR) ? cnt[i] : 0;
  sm[threadIdx.x] = v;
  __syncthreads();
  for (int d = 1; d < 256; d <<= 1) {
    int t = (threadIdx.x >= d) ? sm[threadIdx.x - d] : 0;
    __syncthreads();
    sm[threadIdx.x] += t;
    __syncthreads();
  }
  if (i < RR) off[i] = sm[threadIdx.x] - v;
  if (threadIdx.x == 255) bsum[blockIdx.x] = sm[255];
}

__global__ __launch_bounds__(512) void scan_tops(int* __restrict__ bsum, int nb) {
  __shared__ int sm[512];
  int v = (threadIdx.x < nb) ? bsum[threadIdx.x] : 0;
  sm[threadIdx.x] = v;
  __syncthreads();
  for (int d = 1; d < 512; d <<= 1) {
    int t = (threadIdx.x >= d) ? sm[threadIdx.x - d] : 0;
    __syncthreads();
    sm[threadIdx.x] += t;
    __syncthreads();
  }
  if (threadIdx.x < nb) bsum[threadIdx.x] = sm[threadIdx.x] - v;
}

__global__ __launch_bounds__(256) void scan_add(int* __restrict__ off, const int* __restrict__ bsum,
                                                int* __restrict__ cursor) {
  int i = blockIdx.x * 256 + threadIdx.x;
  if (i < RR) {
    int o = off[i] + bsum[blockIdx.x];
    off[i] = o;
    cursor[i] = o;
  }
  if (i == 0) off[RR] = TT * EE;
}

__global__ __launch_bounds__(256) void scatter_kernel(const int* __restrict__ ei, int* __restrict__ cursor,
                                                      int* __restrict__ csr) {
  int idx = blockIdx.x * 256 + threadIdx.x;
  if (idx >= TT * EE) return;
  int t = idx / EE, e = idx - t * EE;
  int src = ei[(t * 2) * EE + e];
  int dst = ei[(t * 2 + 1) * EE + e];
  int pos = atomicAdd(&cursor[t * VV + dst], 1);
  csr[pos] = t * VV + src;
}

// ---- cast xs -> A_hi[:,0:128] (bf16 hi), A_lo[:,0:128] (bf16 lo) ----
__global__ __launch_bounds__(256) void cast_x0(const float* __restrict__ xs, unsigned short* __restrict__ Ahi,
                                               unsigned short* __restrict__ Alo) {
  int idx = blockIdx.x * 256 + threadIdx.x;  // one per float4, RR*32 total
  int row = idx >> 5, c4 = (idx & 31) * 4;
  float4 v = *reinterpret_cast<const float4*>(&xs[(long)row * 128 + c4]);
  ushort4 hs, ls;
  hs.x = f2bf(v.x); hs.y = f2bf(v.y); hs.z = f2bf(v.z); hs.w = f2bf(v.w);
  ls.x = f2bf(v.x - bf2f(hs.x)); ls.y = f2bf(v.y - bf2f(hs.y));
  ls.z = f2bf(v.z - bf2f(hs.z)); ls.w = f2bf(v.w - bf2f(hs.w));
  *reinterpret_cast<ushort4*>(&Ahi[(long)row * 256 + c4]) = hs;
  *reinterpret_cast<ushort4*>(&Alo[(long)row * 128 + c4]) = ls;
}

// ---- build stacked bf16 weight matrix Bp[n][k] (transposed, row stride Ktot) + bias ----
// k regions (size Cin each): 0:hi(Wl/Wres) 1:hi(Wr/0) 2:lo(Wl/Wres) 3:lo(Wr/0) 4:hi(Wl/Wres)
__global__ __launch_bounds__(256) void prep_b(const float* __restrict__ Wl, const float* __restrict__ Wr,
                                              const float* __restrict__ Wres, const float* __restrict__ bc,
                                              const float* __restrict__ bres, int Cin, int Ktot,
                                              unsigned short* __restrict__ Bp, float* __restrict__ bias) {
  int idx = blockIdx.x * 256 + threadIdx.x;
  if (idx >= NOUT * Ktot) return;
  int n = idx / Ktot, k = idx - n * Ktot;
  int reg = k / Cin, kk = k - reg * Cin;
  float w;
  if (reg == 1 || reg == 3)
    w = (n < 160) ? Wr[kk * 160 + n] : 0.f;
  else
    w = (n < 160) ? Wl[kk * 160 + n] : Wres[kk * 64 + (n - 160)];
  unsigned short h = f2bf(w);
  Bp[idx] = (reg == 2 || reg == 3) ? f2bf(w - bf2f(h)) : h;
  if (k == 0) bias[n] = (n < 160) ? bc[n] : bres[n - 160];
}

// ---- gather layer 0 (latency-optimized): mean of bf16-hi rows, 1 wave per row ----
__global__ __launch_bounds__(256) void gather0(const int* __restrict__ off, const int* __restrict__ csr,
                                               const uint* __restrict__ Xhi, uint* __restrict__ Mout) {
  int w = threadIdx.x >> 6;
  int lane = threadIdx.x & 63;
  int row = blockIdx.x * 4 + w;
  int s = off[row], e = off[row + 1];
  float a0 = 0.f, a1 = 0.f;
  int i = s;
  for (; i + 4 <= e; i += 4) {
    int g0 = csr[i], g1 = csr[i + 1], g2 = csr[i + 2], g3 = csr[i + 3];
    uint w0 = Xhi[(long)g0 * 128 + lane];
    uint w1 = Xhi[(long)g1 * 128 + lane];
    uint w2 = Xhi[(long)g2 * 128 + lane];
    uint w3 = Xhi[(long)g3 * 128 + lane];
    a0 += bf2f(w0 & 0xffffu) + bf2f(w1 & 0xffffu) + bf2f(w2 & 0xffffu) + bf2f(w3 & 0xffffu);
    a1 += bf2f(w0 >> 16) + bf2f(w1 >> 16) + bf2f(w2 >> 16) + bf2f(w3 >> 16);
  }
  for (; i < e; i++) {
    uint w0 = Xhi[(long)csr[i] * 128 + lane];
    a0 += bf2f(w0 & 0xffffu);
    a1 += bf2f(w0 >> 16);
  }
  float inv = 1.f / (float)max(e - s, 1);
  uint hp = (uint)f2bf(a0 * inv) | ((uint)f2bf(a1 * inv) << 16);
  Mout[(long)row * 128 + 64 + lane] = hp;
}

// ---- gather layer 1: 2 rows per wave (32 lane-pairs each), mean-hi -> cols 64:128 ----
__global__ __launch_bounds__(256) void gather1(const int* __restrict__ off, const int* __restrict__ csr,
                                               const uint* __restrict__ Xhi, uint* __restrict__ Mout) {
  int w = threadIdx.x >> 6;
  int lane = threadIdx.x & 63;
  int sub = lane >> 5;
  int p = lane & 31;
  int row = blockIdx.x * 8 + w * 2 + sub;
  int s = off[row], e = off[row + 1];
  float a0 = 0.f, a1 = 0.f;
  int i = s;
  for (; i + 4 <= e; i += 4) {
    int g0 = csr[i], g1 = csr[i + 1], g2 = csr[i + 2], g3 = csr[i + 3];
    uint w0 = Xhi[(long)g0 * 128 + p];
    uint w1 = Xhi[(long)g1 * 128 + p];
    uint w2 = Xhi[(long)g2 * 128 + p];
    uint w3 = Xhi[(long)g3 * 128 + p];
    a0 += bf2f(w0 & 0xffffu) + bf2f(w1 & 0xffffu) + bf2f(w2 & 0xffffu) + bf2f(w3 & 0xffffu);
    a1 += bf2f(w0 >> 16) + bf2f(w1 >> 16) + bf2f(w2 >> 16) + bf2f(w3 >> 16);
  }
  for (; i < e; i++) {
    uint w0 = Xhi[(long)csr[i] * 128 + p];
    a0 += bf2f(w0 & 0xffffu);
    a1 += bf2f(w0 >> 16);
  }
  float inv = 1.f / (float)max(e - s, 1);
  uint hp = (uint)f2bf(a0 * inv) | ((uint)f2bf(a1 * inv) << 16);
  Mout[(long)row * 128 + 32 + p] = hp;
}

// ==== bf16x3 MFMA GEMM, 2-phase double-buffered pipeline ====
// Tile 128x224, BK=64, 8 waves (512 thr). LDS per buffer: A 16KB [128 rows x 128B]
// then B 32KB [256 rows x 128B] (rows >=224 clamped garbage). 16B-granule XOR swizzle
// (c16 ^= row&7): applied on the GLOBAL source during global_load_lds staging and on
// the ds_read address — both sides, LDS dest stays linear (m104/m231 rule).
__device__ __forceinline__ void stage_tile(char* sb, const unsigned short* aptr, long astr,
                                           const unsigned short* Bp, int Ktot, int k0, long row0,
                                           int wid, int lane) {
#pragma unroll
  for (int r = 0; r < 6; ++r) {
    int c = wid * 6 + r;  // 48 chunks of 1024B; 0-15 = A, 16-47 = B (wave-uniform)
    const char* gp;
    if (c < 16) {
      int o = c * 1024 + lane * 16;
      int arow = o >> 7;
      int ac16 = (o >> 4) & 7;
      gp = (const char*)aptr + ((row0 + arow) * astr) * 2 + ((ac16 ^ (arow & 7)) << 4);
    } else {
      int o = (c - 16) * 1024 + lane * 16;
      int brow = o >> 7;
      int bc16 = (o >> 4) & 7;
      int browc = brow < NOUT ? brow : (NOUT - 1);
      gp = (const char*)Bp + ((long)browc * Ktot + k0) * 2 + ((bc16 ^ (brow & 7)) << 4);
    }
    __builtin_amdgcn_global_load_lds((const GLOBAL_AS uint*)gp, (LDS_AS uint*)(sb + c * 1024), 16, 0, 0);
  }
}

__global__ __launch_bounds__(512) void gemm_kernel(const unsigned short* __restrict__ Ahi,
                                                   const unsigned short* __restrict__ Alo,
                                                   const unsigned short* __restrict__ Bp,
                                                   const float* __restrict__ bias, float* __restrict__ outs,
                                                   int Ktot, int sw1, int sw2, int lda, int ldalo) {
  __shared__ char sbuf[2][49152];
  const int tid = threadIdx.x;
  const long row0 = (long)blockIdx.x * 128;
  const int wid = tid >> 6, lane = tid & 63;
  const int wr = wid >> 1, wc = wid & 1;  // wave = 32 rows x 112 cols
  const int l15 = lane & 15, lg = lane >> 4;
  f32x4 acc[2][7];
#pragma unroll
  for (int i = 0; i < 2; i++)
#pragma unroll
    for (int n = 0; n < 7; n++) acc[i][n] = (f32x4)(0.f);

  const int nt = Ktot / 64;
  // region select for tile k0
  auto asel = [&](int k0, const unsigned short*& aptr, long& astr) {
    if (k0 < sw1) { aptr = Ahi + k0; astr = lda; }
    else if (k0 < sw2) { aptr = Ahi + (k0 - sw1); astr = lda; }
    else { aptr = Alo + (k0 - sw2); astr = ldalo; }
  };
  {
    const unsigned short* aptr; long astr;
    asel(0, aptr, astr);
    stage_tile(sbuf[0], aptr, astr, Bp, Ktot, 0, row0, wid, lane);
  }
  for (int kt = 0; kt < nt; ++kt) {
    const int b = kt & 1;
    if (kt + 1 < nt) {
      const unsigned short* aptr; long astr;
      asel((kt + 1) * 64, aptr, astr);
      stage_tile(sbuf[b ^ 1], aptr, astr, Bp, Ktot, (kt + 1) * 64, row0, wid, lane);
      asm volatile("s_waitcnt vmcnt(6)" ::: "memory");  // current buf's 6 loads landed
    } else {
      asm volatile("s_waitcnt vmcnt(0)" ::: "memory");
    }
    __builtin_amdgcn_s_barrier();
    __builtin_amdgcn_sched_barrier(0);
    const char* sb = sbuf[b];
#pragma unroll
    for (int kk = 0; kk < 2; ++kk) {
      const int cswz = (((kk << 2) | lg) ^ (l15 & 7)) << 4;
      bf16x8 af0 = *reinterpret_cast<const bf16x8*>(sb + (wr * 32 + l15) * 128 + cswz);
      bf16x8 af1 = *reinterpret_cast<const bf16x8*>(sb + (wr * 32 + 16 + l15) * 128 + cswz);
#pragma unroll
      for (int n = 0; n < 7; ++n) {
        bf16x8 bfr = *reinterpret_cast<const bf16x8*>(sb + 16384 + (wc * 112 + n * 16 + l15) * 128 + cswz);
        acc[0][n] = __builtin_amdgcn_mfma_f32_16x16x32_bf16(af0, bfr, acc[0][n], 0, 0, 0);
        acc[1][n] = __builtin_amdgcn_mfma_f32_16x16x32_bf16(af1, bfr, acc[1][n], 0, 0, 0);
      }
    }
    __builtin_amdgcn_sched_barrier(0);
    __builtin_amdgcn_s_barrier();  // all waves done reading buf b (next iter overwrites it)
  }
#pragma unroll
  for (int i = 0; i < 2; i++) {
    long grow = row0 + wr * 32 + i * 16 + lg * 4;
#pragma unroll
    for (int n = 0; n < 7; n++) {
      int gcol = wc * 112 + n * 16 + l15;
      float bv = bias[gcol];
#pragma unroll
      for (int r = 0; r < 4; r++) outs[(grow + r) * NOUT + gcol] = acc[i][n][r] + bv;
    }
  }
}

// ---- diagonal SSM scan over T (token-mix inlined for layer 0) ----
// outs row layout: [xh(64) | dts(64) | Bs(16) | Cs(16) | xsr(64)]
__global__ __launch_bounds__(256) void ssm_kernel(const float* __restrict__ outs, const float* __restrict__ logA,
                                                  const float* __restrict__ dlt, const float* __restrict__ tkw,
                                                  const float* __restrict__ tkb, unsigned short* __restrict__ xhi,
                                                  unsigned short* __restrict__ xlo, float* __restrict__ yfin,
                                                  int mode /*0: tkmix, write bf16 all T; 1: write last T fp32*/) {
  int v = blockIdx.x * 4 + (threadIdx.x >> 6);
  int h = threadIdx.x & 63;
  float A[NN], s[NN];
#pragma unroll
  for (int n = 0; n < NN; n++) {
    A[n] = -__expf(logA[h * NN + n]);
    s[n] = 0.f;
  }
  float dh = dlt[h];
  float w0 = 0.f, w1 = 0.f, w2 = 0.f, tb = 0.f;
  float xhm = 0.f, xh0 = 0.f;
  if (mode == 0) {
    w0 = tkw[h * 3 + 0];
    w1 = tkw[h * 3 + 1];
    w2 = tkw[h * 3 + 2];
    tb = tkb[h];
    xh0 = outs[(long)v * NOUT + h];
  }
  for (int t = 0; t < TT; t++) {
    long row = (long)t * VV + v;
    float dtr = outs[row * NOUT + HH + h] + dh;
    float dt = dtr > 20.f ? dtr : log1pf(__expf(dtr));
    float xv;
    if (mode == 0) {
      float xh1 = (t < TT - 1) ? outs[(row + VV) * NOUT + h] : 0.f;
      xv = fmaf(xhm, w0, fmaf(xh0, w1, fmaf(xh1, w2, tb)));
      xhm = xh0;
      xh0 = xh1;
    } else {
      xv = outs[row * NOUT + h];
    }
    float r = outs[row * NOUT + 160 + h];
    float y = 0.f;
#pragma unroll
    for (int n = 0; n < NN; n++) {
      float Bn = outs[row * NOUT + 2 * HH + n];
      float Cn = outs[row * NOUT + 2 * HH + NN + n];
      s[n] = fmaf(__expf(dt * A[n]), s[n], dt * Bn * xv);
      y = fmaf(s[n], Cn, y);
    }
    y = fmaxf(y, 0.f);
    float z = y + r;
    float m = wave_sum64(z) * (1.f / 64.f);
    float d = z - m;
    float var = wave_sum64(d * d) * (1.f / 64.f);
    float o = d * rsqrtf(var + 1e-5f);
    if (mode == 0) {
      unsigned short hi = f2bf(o);
      xhi[row * 256 + h] = hi;
      xlo[row * 128 + h] = f2bf(o - bf2f(hi));
    } else if (t == TT - 1) {
      yfin[(long)v * HH + h] = o;
    }
  }
}

// ---- final [V,64] @ [64,64] + b ----
__global__ __launch_bounds__(256) void final_kernel(const float* __restrict__ y, const float* __restrict__ W,
                                                    const float* __restrict__ b, float* __restrict__ out) {
  int idx = blockIdx.x * 256 + threadIdx.x;
  if (idx >= VV * CO) return;
  int j = idx & 63;
  int v = idx >> 6;
  float acc = b[j];
#pragma unroll
  for (int h = 0; h < HH; h++) acc = fmaf(y[v * HH + h], W[h * CO + j], acc);
  out[idx] = acc;
}

extern "C" void kernel_launch(void* const* d_in, const int* in_sizes, int n_in, void* d_out, int out_size,
                              void* d_ws, size_t ws_size, hipStream_t stream) {
  const float* xs = (const float*)d_in[0];
  const int* ei = (const int*)d_in[1];
  const float* Wl0 = (const float*)d_in[2];
  const float* Wr0 = (const float*)d_in[3];
  const float* bc0 = (const float*)d_in[4];
  const float* Wl1 = (const float*)d_in[5];
  const float* Wr1 = (const float*)d_in[6];
  const float* bc1 = (const float*)d_in[7];
  const float* Wres0 = (const float*)d_in[8];
  const float* bres0 = (const float*)d_in[9];
  const float* Wres1 = (const float*)d_in[10];
  const float* bres1 = (const float*)d_in[11];
  const float* tkw = (const float*)d_in[12];
  const float* tkb = (const float*)d_in[13];
  const float* logA = (const float*)d_in[14];
  const float* dlt = (const float*)d_in[15];
  const float* Wmlp = (const float*)d_in[16];
  const float* bmlp = (const float*)d_in[17];
  float* out = (float*)d_out;

  float* outs = (float*)d_ws;                          // RR*224 f32
  unsigned short* Ahi = (unsigned short*)(outs + (long)RR * NOUT);  // RR*256 bf16
  unsigned short* Alo = Ahi + (long)RR * 256;          // RR*128 bf16
  unsigned short* Bp0 = Alo + (long)RR * 128;          // 224*640
  unsigned short* Bp1 = Bp0 + 224 * 640;               // 224*320
  float* bias0 = (float*)(Bp1 + 224 * 320);            // 224
  float* bias1 = bias0 + 224;                          // 224
  float* yfin = bias1 + 224;                           // VV*64
  int* cnt = (int*)(yfin + (long)VV * 64);             // RR
  int* off = cnt + RR;                                 // RR+1
  int* cursor = off + RR + 1;                          // RR
  int* bsum = cursor + RR;                             // 512
  int* csr = bsum + 512;                               // TT*EE

  const int NB = (RR + 255) / 256;

  // ---- CSR build (edges shared by both layers) ----
  hipMemsetAsync(cnt, 0, RR * sizeof(int), stream);
  count_kernel<<<(TT * EE + 255) / 256, 256, 0, stream>>>(ei, cnt);
  scan_block<<<NB, 256, 0, stream>>>(cnt, off, bsum);
  scan_tops<<<1, 512, 0, stream>>>(bsum, NB);
  scan_add<<<NB, 256, 0, stream>>>(off, bsum, cursor);
  scatter_kernel<<<(TT * EE + 255) / 256, 256, 0, stream>>>(ei, cursor, csr);

  // ---- weight prep ----
  prep_b<<<(NOUT * 640 + 255) / 256, 256, 0, stream>>>(Wl0, Wr0, Wres0, bc0, bres0, 128, 640, Bp0, bias0);
  prep_b<<<(NOUT * 320 + 255) / 256, 256, 0, stream>>>(Wl1, Wr1, Wres1, bc1, bres1, 64, 320, Bp1, bias1);

  // ---- layer 0 ----
  cast_x0<<<RR * 32 / 256, 256, 0, stream>>>(xs, Ahi, Alo);
  gather0<<<RR / 4, 256, 0, stream>>>(off, csr, (const uint*)Ahi, (uint*)Ahi);
  gemm_kernel<<<RR / 128, 512, 0, stream>>>(Ahi, Alo, Bp0, bias0, outs, 640, 256, 512, 256, 128);
  ssm_kernel<<<VV / 4, 256, 0, stream>>>(outs, logA, dlt, tkw, tkb, Ahi, Alo, nullptr, 0);

  // ---- layer 1 ----
  gather1<<<RR / 8, 256, 0, stream>>>(off, csr, (const uint*)Ahi, (uint*)Ahi);
  gemm_kernel<<<RR / 128, 512, 0, stream>>>(Ahi, Alo, Bp1, bias1, outs, 320, 128, 256, 256, 128);
  ssm_kernel<<<VV / 4, 256, 0, stream>>>(outs, logA + HH * NN, dlt + HH, nullptr, nullptr, nullptr, nullptr, yfin, 1);

  // ---- head ----
  final_kernel<<<(VV * CO) / 256, 256, 0, stream>>>(yfin, Wmlp, bmlp, out);
}

// Round 6
// 368.220 us; speedup vs baseline: 10.3953x; 1.1334x over previous
//
#include <hip/hip_runtime.h>

#define TT 8
#define VV 10000
#define EE 160000
#define HH 64
#define NN 16
#define CO 64
#define NOUT 224  // 160 conv outs + 64 residual
#define RR (TT * VV)

typedef float f32x4 __attribute__((ext_vector_type(4)));
typedef __bf16 bf16x8 __attribute__((ext_vector_type(8)));
typedef unsigned int uint;

#define GLOBAL_AS __attribute__((address_space(1)))
#define LDS_AS __attribute__((address_space(3)))

__device__ __forceinline__ unsigned short f2bf(float f) {
  union { float f; unsigned u; } v;
  v.f = f;
  unsigned r = v.u + 0x7fffu + ((v.u >> 16) & 1u);
  return (unsigned short)(r >> 16);
}
__device__ __forceinline__ float bf2f(unsigned h) {
  union { unsigned u; float f; } v;
  v.u = h << 16;
  return v.f;
}

__device__ __forceinline__ float wave_sum64(float v) {
#pragma unroll
  for (int m = 32; m > 0; m >>= 1) v += __shfl_xor(v, m, 64);
  return v;
}

// ---- in-degree counts + per-edge rank (atomic return) ----
__global__ __launch_bounds__(256) void count_rank_kernel(const int* __restrict__ ei, int* __restrict__ cnt,
                                                         int* __restrict__ rank) {
  int idx = blockIdx.x * 256 + threadIdx.x;
  if (idx >= TT * EE) return;
  int t = idx / EE, e = idx - t * EE;
  int dst = ei[(t * 2 + 1) * EE + e];
  rank[idx] = atomicAdd(&cnt[t * VV + dst], 1);
}

// ---- CSR build: block-level exclusive scan ----
__global__ __launch_bounds__(256) void scan_block(const int* __restrict__ cnt, int* __restrict__ off,
                                                  int* __restrict__ bsum) {
  __shared__ int sm[256];
  int i = blockIdx.x * 256 + threadIdx.x;
  int v = (i < RR) ? cnt[i] : 0;
  sm[threadIdx.x] = v;
  __syncthreads();
  for (int d = 1; d < 256; d <<= 1) {
    int t = (threadIdx.x >= d) ? sm[threadIdx.x - d] : 0;
    __syncthreads();
    sm[threadIdx.x] += t;
    __syncthreads();
  }
  if (i < RR) off[i] = sm[threadIdx.x] - v;
  if (threadIdx.x == 255) bsum[blockIdx.x] = sm[255];
}

__global__ __launch_bounds__(512) void scan_tops(int* __restrict__ bsum, int nb) {
  __shared__ int sm[512];
  int v = (threadIdx.x < nb) ? bsum[threadIdx.x] : 0;
  sm[threadIdx.x] = v;
  __syncthreads();
  for (int d = 1; d < 512; d <<= 1) {
    int t = (threadIdx.x >= d) ? sm[threadIdx.x - d] : 0;
    __syncthreads();
    sm[threadIdx.x] += t;
    __syncthreads();
  }
  if (threadIdx.x < nb) bsum[threadIdx.x] = sm[threadIdx.x] - v;
}

__global__ __launch_bounds__(256) void scan_add(int* __restrict__ off, const int* __restrict__ bsum) {
  int i = blockIdx.x * 256 + threadIdx.x;
  if (i < RR) off[i] += bsum[blockIdx.x];
  if (i == 0) off[RR] = TT * EE;
}

// ---- atomic-free scatter: csr[off[dst] + rank[e]] = src ----
__global__ __launch_bounds__(256) void scatter_kernel(const int* __restrict__ ei, const int* __restrict__ off,
                                                      const int* __restrict__ rank, int* __restrict__ csr) {
  int idx = blockIdx.x * 256 + threadIdx.x;
  if (idx >= TT * EE) return;
  int t = idx / EE, e = idx - t * EE;
  int src = ei[(t * 2) * EE + e];
  int dst = ei[(t * 2 + 1) * EE + e];
  csr[off[t * VV + dst] + rank[idx]] = t * VV + src;
}

// ---- cast xs -> A_hi[:,0:128] (bf16 hi), A_lo[:,0:128] (bf16 lo) ----
__global__ __launch_bounds__(256) void cast_x0(const float* __restrict__ xs, unsigned short* __restrict__ Ahi,
                                               unsigned short* __restrict__ Alo) {
  int idx = blockIdx.x * 256 + threadIdx.x;  // one per float4, RR*32 total
  int row = idx >> 5, c4 = (idx & 31) * 4;
  float4 v = *reinterpret_cast<const float4*>(&xs[(long)row * 128 + c4]);
  ushort4 hs, ls;
  hs.x = f2bf(v.x); hs.y = f2bf(v.y); hs.z = f2bf(v.z); hs.w = f2bf(v.w);
  ls.x = f2bf(v.x - bf2f(hs.x)); ls.y = f2bf(v.y - bf2f(hs.y));
  ls.z = f2bf(v.z - bf2f(hs.z)); ls.w = f2bf(v.w - bf2f(hs.w));
  *reinterpret_cast<ushort4*>(&Ahi[(long)row * 256 + c4]) = hs;
  *reinterpret_cast<ushort4*>(&Alo[(long)row * 128 + c4]) = ls;
}

// ---- build stacked bf16 weight matrix Bp[n][k] (transposed, row stride Ktot) + bias ----
// k regions (size Cin each): 0:hi(Wl/Wres) 1:hi(Wr/0) 2:lo(Wl/Wres) 3:lo(Wr/0) 4:hi(Wl/Wres)
__global__ __launch_bounds__(256) void prep_b(const float* __restrict__ Wl, const float* __restrict__ Wr,
                                              const float* __restrict__ Wres, const float* __restrict__ bc,
                                              const float* __restrict__ bres, int Cin, int Ktot,
                                              unsigned short* __restrict__ Bp, float* __restrict__ bias) {
  int idx = blockIdx.x * 256 + threadIdx.x;
  if (idx >= NOUT * Ktot) return;
  int n = idx / Ktot, k = idx - n * Ktot;
  int reg = k / Cin, kk = k - reg * Cin;
  float w;
  if (reg == 1 || reg == 3)
    w = (n < 160) ? Wr[kk * 160 + n] : 0.f;
  else
    w = (n < 160) ? Wl[kk * 160 + n] : Wres[kk * 64 + (n - 160)];
  unsigned short h = f2bf(w);
  Bp[idx] = (reg == 2 || reg == 3) ? f2bf(w - bf2f(h)) : h;
  if (k == 0) bias[n] = (n < 160) ? bc[n] : bres[n - 160];
}

// ---- gather layer 0 (latency-optimized): mean of bf16-hi rows, 1 wave per row ----
__global__ __launch_bounds__(256) void gather0(const int* __restrict__ off, const int* __restrict__ csr,
                                               const uint* __restrict__ Xhi, uint* __restrict__ Mout) {
  int w = threadIdx.x >> 6;
  int lane = threadIdx.x & 63;
  int row = blockIdx.x * 4 + w;
  int s = off[row], e = off[row + 1];
  float a0 = 0.f, a1 = 0.f;
  int i = s;
  for (; i + 4 <= e; i += 4) {
    int g0 = csr[i], g1 = csr[i + 1], g2 = csr[i + 2], g3 = csr[i + 3];
    uint w0 = Xhi[(long)g0 * 128 + lane];
    uint w1 = Xhi[(long)g1 * 128 + lane];
    uint w2 = Xhi[(long)g2 * 128 + lane];
    uint w3 = Xhi[(long)g3 * 128 + lane];
    a0 += bf2f(w0 & 0xffffu) + bf2f(w1 & 0xffffu) + bf2f(w2 & 0xffffu) + bf2f(w3 & 0xffffu);
    a1 += bf2f(w0 >> 16) + bf2f(w1 >> 16) + bf2f(w2 >> 16) + bf2f(w3 >> 16);
  }
  for (; i < e; i++) {
    uint w0 = Xhi[(long)csr[i] * 128 + lane];
    a0 += bf2f(w0 & 0xffffu);
    a1 += bf2f(w0 >> 16);
  }
  float inv = 1.f / (float)max(e - s, 1);
  uint hp = (uint)f2bf(a0 * inv) | ((uint)f2bf(a1 * inv) << 16);
  Mout[(long)row * 128 + 64 + lane] = hp;
}

// ---- gather layer 1: 2 rows per wave (32 lane-pairs each), mean-hi -> cols 64:128 ----
__global__ __launch_bounds__(256) void gather1(const int* __restrict__ off, const int* __restrict__ csr,
                                               const uint* __restrict__ Xhi, uint* __restrict__ Mout) {
  int w = threadIdx.x >> 6;
  int lane = threadIdx.x & 63;
  int sub = lane >> 5;
  int p = lane & 31;
  int row = blockIdx.x * 8 + w * 2 + sub;
  int s = off[row], e = off[row + 1];
  float a0 = 0.f, a1 = 0.f;
  int i = s;
  for (; i + 4 <= e; i += 4) {
    int g0 = csr[i], g1 = csr[i + 1], g2 = csr[i + 2], g3 = csr[i + 3];
    uint w0 = Xhi[(long)g0 * 128 + p];
    uint w1 = Xhi[(long)g1 * 128 + p];
    uint w2 = Xhi[(long)g2 * 128 + p];
    uint w3 = Xhi[(long)g3 * 128 + p];
    a0 += bf2f(w0 & 0xffffu) + bf2f(w1 & 0xffffu) + bf2f(w2 & 0xffffu) + bf2f(w3 & 0xffffu);
    a1 += bf2f(w0 >> 16) + bf2f(w1 >> 16) + bf2f(w2 >> 16) + bf2f(w3 >> 16);
  }
  for (; i < e; i++) {
    uint w0 = Xhi[(long)csr[i] * 128 + p];
    a0 += bf2f(w0 & 0xffffu);
    a1 += bf2f(w0 >> 16);
  }
  float inv = 1.f / (float)max(e - s, 1);
  uint hp = (uint)f2bf(a0 * inv) | ((uint)f2bf(a1 * inv) << 16);
  Mout[(long)row * 128 + 32 + p] = hp;
}

// ==== bf16x3 MFMA GEMM, 2-phase double-buffered pipeline ====
// Tile 128x224, BK=64, 8 waves (512 thr). LDS per buffer: A 16KB [128 rows x 128B]
// then B 32KB [256 rows x 128B] (rows >=224 clamped garbage). 16B-granule XOR swizzle
// (c16 ^= row&7): applied on the GLOBAL source during global_load_lds staging and on
// the ds_read address — both sides, LDS dest stays linear (m104/m231 rule).
__device__ __forceinline__ void stage_tile(char* sb, const unsigned short* aptr, long astr,
                                           const unsigned short* Bp, int Ktot, int k0, long row0,
                                           int wid, int lane) {
#pragma unroll
  for (int r = 0; r < 6; ++r) {
    int c = wid * 6 + r;  // 48 chunks of 1024B; 0-15 = A, 16-47 = B (wave-uniform)
    const char* gp;
    if (c < 16) {
      int o = c * 1024 + lane * 16;
      int arow = o >> 7;
      int ac16 = (o >> 4) & 7;
      gp = (const char*)aptr + ((row0 + arow) * astr) * 2 + ((ac16 ^ (arow & 7)) << 4);
    } else {
      int o = (c - 16) * 1024 + lane * 16;
      int brow = o >> 7;
      int bc16 = (o >> 4) & 7;
      int browc = brow < NOUT ? brow : (NOUT - 1);
      gp = (const char*)Bp + ((long)browc * Ktot + k0) * 2 + ((bc16 ^ (brow & 7)) << 4);
    }
    __builtin_amdgcn_global_load_lds((const GLOBAL_AS uint*)gp, (LDS_AS uint*)(sb + c * 1024), 16, 0, 0);
  }
}

__global__ __launch_bounds__(512) void gemm_kernel(const unsigned short* __restrict__ Ahi,
                                                   const unsigned short* __restrict__ Alo,
                                                   const unsigned short* __restrict__ Bp,
                                                   const float* __restrict__ bias, float* __restrict__ outs,
                                                   int Ktot, int sw1, int sw2, int lda, int ldalo) {
  __shared__ char sbuf[2][49152];
  const int tid = threadIdx.x;
  const long row0 = (long)blockIdx.x * 128;
  const int wid = tid >> 6, lane = tid & 63;
  const int wr = wid >> 1, wc = wid & 1;  // wave = 32 rows x 112 cols
  const int l15 = lane & 15, lg = lane >> 4;
  f32x4 acc[2][7];
#pragma unroll
  for (int i = 0; i < 2; i++)
#pragma unroll
    for (int n = 0; n < 7; n++) acc[i][n] = (f32x4)(0.f);

  const int nt = Ktot / 64;
  // region select for tile k0
  auto asel = [&](int k0, const unsigned short*& aptr, long& astr) {
    if (k0 < sw1) { aptr = Ahi + k0; astr = lda; }
    else if (k0 < sw2) { aptr = Ahi + (k0 - sw1); astr = lda; }
    else { aptr = Alo + (k0 - sw2); astr = ldalo; }
  };
  {
    const unsigned short* aptr; long astr;
    asel(0, aptr, astr);
    stage_tile(sbuf[0], aptr, astr, Bp, Ktot, 0, row0, wid, lane);
  }
  for (int kt = 0; kt < nt; ++kt) {
    const int b = kt & 1;
    if (kt + 1 < nt) {
      const unsigned short* aptr; long astr;
      asel((kt + 1) * 64, aptr, astr);
      stage_tile(sbuf[b ^ 1], aptr, astr, Bp, Ktot, (kt + 1) * 64, row0, wid, lane);
      asm volatile("s_waitcnt vmcnt(6)" ::: "memory");  // current buf's 6 loads landed
    } else {
      asm volatile("s_waitcnt vmcnt(0)" ::: "memory");
    }
    __builtin_amdgcn_s_barrier();
    __builtin_amdgcn_sched_barrier(0);
    const char* sb = sbuf[b];
#pragma unroll
    for (int kk = 0; kk < 2; ++kk) {
      const int cswz = (((kk << 2) | lg) ^ (l15 & 7)) << 4;
      bf16x8 af0 = *reinterpret_cast<const bf16x8*>(sb + (wr * 32 + l15) * 128 + cswz);
      bf16x8 af1 = *reinterpret_cast<const bf16x8*>(sb + (wr * 32 + 16 + l15) * 128 + cswz);
#pragma unroll
      for (int n = 0; n < 7; ++n) {
        bf16x8 bfr = *reinterpret_cast<const bf16x8*>(sb + 16384 + (wc * 112 + n * 16 + l15) * 128 + cswz);
        acc[0][n] = __builtin_amdgcn_mfma_f32_16x16x32_bf16(af0, bfr, acc[0][n], 0, 0, 0);
        acc[1][n] = __builtin_amdgcn_mfma_f32_16x16x32_bf16(af1, bfr, acc[1][n], 0, 0, 0);
      }
    }
    __builtin_amdgcn_sched_barrier(0);
    __builtin_amdgcn_s_barrier();  // all waves done reading buf b (next iter overwrites it)
  }
#pragma unroll
  for (int i = 0; i < 2; i++) {
    long grow = row0 + wr * 32 + i * 16 + lg * 4;
#pragma unroll
    for (int n = 0; n < 7; n++) {
      int gcol = wc * 112 + n * 16 + l15;
      float bv = bias[gcol];
#pragma unroll
      for (int r = 0; r < 4; r++) outs[(grow + r) * NOUT + gcol] = acc[i][n][r] + bv;
    }
  }
}

// ---- diagonal SSM scan over T (token-mix inlined for layer 0) ----
// outs row layout: [xh(64) | dts(64) | Bs(16) | Cs(16) | xsr(64)]
__global__ __launch_bounds__(256) void ssm_kernel(const float* __restrict__ outs, const float* __restrict__ logA,
                                                  const float* __restrict__ dlt, const float* __restrict__ tkw,
                                                  const float* __restrict__ tkb, unsigned short* __restrict__ xhi,
                                                  unsigned short* __restrict__ xlo, float* __restrict__ yfin,
                                                  int mode /*0: tkmix, write bf16 all T; 1: write last T fp32*/) {
  int v = blockIdx.x * 4 + (threadIdx.x >> 6);
  int h = threadIdx.x & 63;
  float A[NN], s[NN];
#pragma unroll
  for (int n = 0; n < NN; n++) {
    A[n] = -__expf(logA[h * NN + n]);
    s[n] = 0.f;
  }
  float dh = dlt[h];
  float w0 = 0.f, w1 = 0.f, w2 = 0.f, tb = 0.f;
  float xhm = 0.f, xh0 = 0.f;
  if (mode == 0) {
    w0 = tkw[h * 3 + 0];
    w1 = tkw[h * 3 + 1];
    w2 = tkw[h * 3 + 2];
    tb = tkb[h];
    xh0 = outs[(long)v * NOUT + h];
  }
  for (int t = 0; t < TT; t++) {
    long row = (long)t * VV + v;
    float dtr = outs[row * NOUT + HH + h] + dh;
    float dt = dtr > 20.f ? dtr : log1pf(__expf(dtr));
    float xv;
    if (mode == 0) {
      float xh1 = (t < TT - 1) ? outs[(row + VV) * NOUT + h] : 0.f;
      xv = fmaf(xhm, w0, fmaf(xh0, w1, fmaf(xh1, w2, tb)));
      xhm = xh0;
      xh0 = xh1;
    } else {
      xv = outs[row * NOUT + h];
    }
    float r = outs[row * NOUT + 160 + h];
    float y = 0.f;
#pragma unroll
    for (int n = 0; n < NN; n++) {
      float Bn = outs[row * NOUT + 2 * HH + n];
      float Cn = outs[row * NOUT + 2 * HH + NN + n];
      s[n] = fmaf(__expf(dt * A[n]), s[n], dt * Bn * xv);
      y = fmaf(s[n], Cn, y);
    }
    y = fmaxf(y, 0.f);
    float z = y + r;
    float m = wave_sum64(z) * (1.f / 64.f);
    float d = z - m;
    float var = wave_sum64(d * d) * (1.f / 64.f);
    float o = d * rsqrtf(var + 1e-5f);
    if (mode == 0) {
      unsigned short hi = f2bf(o);
      xhi[row * 256 + h] = hi;
      xlo[row * 128 + h] = f2bf(o - bf2f(hi));
    } else if (t == TT - 1) {
      yfin[(long)v * HH + h] = o;
    }
  }
}

// ---- final [V,64] @ [64,64] + b ----
__global__ __launch_bounds__(256) void final_kernel(const float* __restrict__ y, const float* __restrict__ W,
                                                    const float* __restrict__ b, float* __restrict__ out) {
  int idx = blockIdx.x * 256 + threadIdx.x;
  if (idx >= VV * CO) return;
  int j = idx & 63;
  int v = idx >> 6;
  float acc = b[j];
#pragma unroll
  for (int h = 0; h < HH; h++) acc = fmaf(y[v * HH + h], W[h * CO + j], acc);
  out[idx] = acc;
}

extern "C" void kernel_launch(void* const* d_in, const int* in_sizes, int n_in, void* d_out, int out_size,
                              void* d_ws, size_t ws_size, hipStream_t stream) {
  const float* xs = (const float*)d_in[0];
  const int* ei = (const int*)d_in[1];
  const float* Wl0 = (const float*)d_in[2];
  const float* Wr0 = (const float*)d_in[3];
  const float* bc0 = (const float*)d_in[4];
  const float* Wl1 = (const float*)d_in[5];
  const float* Wr1 = (const float*)d_in[6];
  const float* bc1 = (const float*)d_in[7];
  const float* Wres0 = (const float*)d_in[8];
  const float* bres0 = (const float*)d_in[9];
  const float* Wres1 = (const float*)d_in[10];
  const float* bres1 = (const float*)d_in[11];
  const float* tkw = (const float*)d_in[12];
  const float* tkb = (const float*)d_in[13];
  const float* logA = (const float*)d_in[14];
  const float* dlt = (const float*)d_in[15];
  const float* Wmlp = (const float*)d_in[16];
  const float* bmlp = (const float*)d_in[17];
  float* out = (float*)d_out;

  float* outs = (float*)d_ws;                          // RR*224 f32
  unsigned short* Ahi = (unsigned short*)(outs + (long)RR * NOUT);  // RR*256 bf16
  unsigned short* Alo = Ahi + (long)RR * 256;          // RR*128 bf16
  unsigned short* Bp0 = Alo + (long)RR * 128;          // 224*640
  unsigned short* Bp1 = Bp0 + 224 * 640;               // 224*320
  float* bias0 = (float*)(Bp1 + 224 * 320);            // 224
  float* bias1 = bias0 + 224;                          // 224
  float* yfin = bias1 + 224;                           // VV*64
  int* cnt = (int*)(yfin + (long)VV * 64);             // RR
  int* off = cnt + RR;                                 // RR+1
  int* bsum = off + RR + 1;                            // 512
  int* rank = bsum + 512;                              // TT*EE
  int* csr = rank + TT * EE;                           // TT*EE

  const int NB = (RR + 255) / 256;

  // ---- CSR build (edges shared by both layers), atomic-free scatter via rank ----
  hipMemsetAsync(cnt, 0, RR * sizeof(int), stream);
  count_rank_kernel<<<(TT * EE + 255) / 256, 256, 0, stream>>>(ei, cnt, rank);
  scan_block<<<NB, 256, 0, stream>>>(cnt, off, bsum);
  scan_tops<<<1, 512, 0, stream>>>(bsum, NB);
  scan_add<<<NB, 256, 0, stream>>>(off, bsum);
  scatter_kernel<<<(TT * EE + 255) / 256, 256, 0, stream>>>(ei, off, rank, csr);

  // ---- weight prep ----
  prep_b<<<(NOUT * 640 + 255) / 256, 256, 0, stream>>>(Wl0, Wr0, Wres0, bc0, bres0, 128, 640, Bp0, bias0);
  prep_b<<<(NOUT * 320 + 255) / 256, 256, 0, stream>>>(Wl1, Wr1, Wres1, bc1, bres1, 64, 320, Bp1, bias1);

  // ---- layer 0 ----
  cast_x0<<<RR * 32 / 256, 256, 0, stream>>>(xs, Ahi, Alo);
  gather0<<<RR / 4, 256, 0, stream>>>(off, csr, (const uint*)Ahi, (uint*)Ahi);
  gemm_kernel<<<RR / 128, 512, 0, stream>>>(Ahi, Alo, Bp0, bias0, outs, 640, 256, 512, 256, 128);
  ssm_kernel<<<VV / 4, 256, 0, stream>>>(outs, logA, dlt, tkw, tkb, Ahi, Alo, nullptr, 0);

  // ---- layer 1 ----
  gather1<<<RR / 8, 256, 0, stream>>>(off, csr, (const uint*)Ahi, (uint*)Ahi);
  gemm_kernel<<<RR / 128, 512, 0, stream>>>(Ahi, Alo, Bp1, bias1, outs, 320, 128, 256, 256, 128);
  ssm_kernel<<<VV / 4, 256, 0, stream>>>(outs, logA + HH * NN, dlt + HH, nullptr, nullptr, nullptr, nullptr, yfin, 1);

  // ---- head ----
  final_kernel<<<(VV * CO) / 256, 256, 0, stream>>>(yfin, Wmlp, bmlp, out);
}